// Round 2
// baseline (10397.053 us; speedup 1.0000x reference)
//
#include <hip/hip_runtime.h>
#include <hip/hip_bf16.h>

// ---------------- constants ----------------
#define BATCH 4
#define TIN0 160000
#define DMODEL 768
#define NLAYER 12
#define NHEAD 12
#define FFDIM 2048
#define NCLS 100
#define SMAX_ 64
#define TP_ 499

// conv stack time sizes per batch:
// T: 160000 ->31999(c0) ->15999(c1) ->7999 ->3999 ->1999 ->999 ->499

// ---------------- reduction helpers ----------------
__device__ inline float wave_reduce_sum(float v) {
#pragma unroll
    for (int off = 32; off > 0; off >>= 1) v += __shfl_down(v, off, 64);
    return v;
}
__device__ inline float wave_reduce_max(float v) {
#pragma unroll
    for (int off = 32; off > 0; off >>= 1) v = fmaxf(v, __shfl_down(v, off, 64));
    return v;
}
// block of exactly 256 threads
__device__ inline float block_reduce_sum(float v, float* scratch) {
    v = wave_reduce_sum(v);
    int wid = threadIdx.x >> 6;
    if ((threadIdx.x & 63) == 0) scratch[wid] = v;
    __syncthreads();
    float r = scratch[0] + scratch[1] + scratch[2] + scratch[3];
    __syncthreads();
    return r;
}
__device__ inline float block_reduce_max(float v, float* scratch) {
    v = wave_reduce_max(v);
    int wid = threadIdx.x >> 6;
    if ((threadIdx.x & 63) == 0) scratch[wid] = v;
    __syncthreads();
    float r = fmaxf(fmaxf(scratch[0], scratch[1]), fmaxf(scratch[2], scratch[3]));
    __syncthreads();
    return r;
}

// ---------------- fused conv0(Cin=1,K=10,s=5) + conv1(Cin=512,K=3,s=2) ----------------
// x [160000] (one batch), w0 [512][10], b0 [512], w1 [512][1536], out [512][15999]
__global__ __launch_bounds__(256) void conv01_fused(const float* __restrict__ x,
                                                    const float* __restrict__ w0,
                                                    const float* __restrict__ b0,
                                                    const float* __restrict__ w1,
                                                    const float* __restrict__ bias1,
                                                    float* __restrict__ out) {
    constexpr int KC = 24;          // 8 input channels x 3 taps per chunk
    constexpr int K = 1536;         // 512*3
    constexpr int Tout = 15999;
    __shared__ float sA[KC][68];    // w1 chunk: [j'][oc']
    __shared__ float sB[KC][68];    // on-the-fly conv0 patches: [j'][t']
    __shared__ float sX[656];       // x window: 10*64 + 19 (need up to 650)
    __shared__ float sW0[512 * 10];
    __shared__ float sB0[512];
    const int oc0 = blockIdx.x * 64;
    const int t0 = blockIdx.y * 64;
    const int tid = threadIdx.x;
    const int tx = tid & 15;   // -> t subtile
    const int ty = tid >> 4;   // -> oc subtile

    // stage all conv0 weights/bias once
    for (int i = tid; i < 512 * 10; i += 256) sW0[i] = w0[i];
    for (int i = tid; i < 512; i += 256) sB0[i] = b0[i];
    // stage x window: global index 10*t0 + i, clamp (tail block only; stores guarded)
    {
        int gbase = 10 * t0;
        for (int i = tid; i < 656; i += 256) {
            int g = gbase + i;
            sX[i] = x[g < TIN0 ? g : TIN0 - 1];
        }
    }
    float acc[4][4];
#pragma unroll
    for (int i = 0; i < 4; i++)
#pragma unroll
        for (int l = 0; l < 4; l++) acc[i][l] = 0.f;
    __syncthreads();

    for (int jc = 0; jc < K; jc += KC) {
#pragma unroll
        for (int idx = tid; idx < KC * 64; idx += 256) {
            int j = idx % KC, ocp = idx / KC;
            sA[j][ocp] = w1[(size_t)(oc0 + ocp) * K + jc + j];
        }
#pragma unroll
        for (int idx = tid; idx < KC * 64; idx += 256) {
            int jp = idx >> 6, tp = idx & 63;
            int jj = jc + jp;
            int ic = jj / 3, k = jj - ic * 3;
            // conv0 value at channel ic, time u = 2*(t0+tp)+k
            const float* xs = &sX[10 * tp + 5 * k];
            const float* wp = &sW0[ic * 10];
            float a = sB0[ic];
#pragma unroll
            for (int q = 0; q < 10; q++) a = fmaf(xs[q], wp[q], a);
            sB[jp][tp] = fmaxf(a, 0.f);
        }
        __syncthreads();
#pragma unroll
        for (int j = 0; j < KC; j++) {
            const float4 av = *(const float4*)&sA[j][ty * 4];
            const float4 bv = *(const float4*)&sB[j][tx * 4];
            const float aa[4] = {av.x, av.y, av.z, av.w};
            const float bb[4] = {bv.x, bv.y, bv.z, bv.w};
#pragma unroll
            for (int i = 0; i < 4; i++)
#pragma unroll
                for (int l = 0; l < 4; l++) acc[i][l] = fmaf(aa[i], bb[l], acc[i][l]);
        }
        __syncthreads();
    }
#pragma unroll
    for (int i = 0; i < 4; i++) {
        int oc = oc0 + ty * 4 + i;
        float bz = bias1[oc];
        size_t obase = (size_t)oc * Tout;
#pragma unroll
        for (int l = 0; l < 4; l++) {
            int t = t0 + tx * 4 + l;
            if (t < Tout) out[obase + t] = fmaxf(acc[i][l] + bz, 0.f);
        }
    }
}

// ---------------- generic conv layer (stride 2), implicit GEMM, one batch ----------------
// in [CIN][Tin] -> out [Cout][Tout], w [Cout][CIN*KW], relu(+bias)
template <int KW, int CIN>
__global__ __launch_bounds__(256) void conv_gemm(const float* __restrict__ in,
                                                 const float* __restrict__ w,
                                                 const float* __restrict__ bias,
                                                 float* __restrict__ out,
                                                 int Cout, int Tin, int Tout) {
    constexpr int KC = 8 * KW;      // 24 (kw=3) or 16 (kw=2)
    constexpr int K = CIN * KW;     // 1536 or 1024
    __shared__ float sA[KC][68];    // weights: [j'][oc']
    __shared__ float sB[KC][68];    // patches: [j'][t']
    const int oc0 = blockIdx.x * 64;
    const int t0 = blockIdx.y * 64;
    const int tid = threadIdx.x;
    const int tx = tid & 15;
    const int ty = tid >> 4;
    float acc[4][4];
#pragma unroll
    for (int i = 0; i < 4; i++)
#pragma unroll
        for (int l = 0; l < 4; l++) acc[i][l] = 0.f;

    for (int jc = 0; jc < K; jc += KC) {
#pragma unroll
        for (int idx = tid; idx < KC * 64; idx += 256) {
            int j = idx % KC, ocp = idx / KC;
            sA[j][ocp] = w[(size_t)(oc0 + ocp) * K + jc + j];
        }
#pragma unroll
        for (int idx = tid; idx < KC * 64; idx += 256) {
            int jp = idx >> 6, tp = idx & 63;
            int jj = jc + jp;
            int ic = jj / KW, k = jj - ic * KW;
            int t = t0 + tp;
            if (t > Tout - 1) t = Tout - 1;  // clamp (stores guarded)
            sB[jp][tp] = in[(size_t)ic * Tin + t * 2 + k];
        }
        __syncthreads();
#pragma unroll
        for (int j = 0; j < KC; j++) {
            const float4 av = *(const float4*)&sA[j][ty * 4];
            const float4 bv = *(const float4*)&sB[j][tx * 4];
            const float aa[4] = {av.x, av.y, av.z, av.w};
            const float bb[4] = {bv.x, bv.y, bv.z, bv.w};
#pragma unroll
            for (int i = 0; i < 4; i++)
#pragma unroll
                for (int l = 0; l < 4; l++) acc[i][l] = fmaf(aa[i], bb[l], acc[i][l]);
        }
        __syncthreads();
    }
#pragma unroll
    for (int i = 0; i < 4; i++) {
        int oc = oc0 + ty * 4 + i;
        float bz = bias[oc];
        size_t obase = (size_t)oc * Tout;
#pragma unroll
        for (int l = 0; l < 4; l++) {
            int t = t0 + tx * 4 + l;
            if (t < Tout) out[obase + t] = fmaxf(acc[i][l] + bz, 0.f);
        }
    }
}

// ---------------- scores: feats[c][t] . attn_v[c]  (one batch) ----------------
__global__ __launch_bounds__(256) void scores_kernel(const float* __restrict__ feats,
                                                     const float* __restrict__ v,
                                                     float* __restrict__ scores) {
    int t = blockIdx.x * 256 + threadIdx.x;
    if (t >= TP_) return;
    const float* f = feats + t;
    float acc = 0.f;
    for (int c = 0; c < DMODEL; c++) acc = fmaf(f[(size_t)c * TP_], v[c], acc);
    scores[t] = acc;
}

// ---------------- per-segment softmax pooling + pos_emb (one batch) ----------------
__global__ __launch_bounds__(256) void pool_kernel(const float* __restrict__ feats,
                                                   const float* __restrict__ scores,
                                                   const int* __restrict__ seg_bounds_b,
                                                   const int* __restrict__ n_segs, int b,
                                                   const float* __restrict__ pos_emb,
                                                   float* __restrict__ tokens_b) {
    __shared__ float scratch[4];
    __shared__ float wgt[512];
    int s = blockIdx.x, tid = threadIdx.x;
    float* tout = tokens_b + (size_t)s * DMODEL;
    int ns = n_segs[b];
    if (s >= ns) {  // padded segment: tokens = 0 + pos_emb
        for (int c = tid; c < DMODEL; c += 256) tout[c] = pos_emb[s * DMODEL + c];
        return;
    }
    int b0 = seg_bounds_b[s];
    int b1 = seg_bounds_b[s + 1];
    int st = min(max(b0, 0), TP_ - 1);
    int en = max(st + 1, min(max(b1, 0), TP_));
    float lm = -1e30f;
    for (int t = st + tid; t < en; t += 256) lm = fmaxf(lm, scores[t]);
    float m = block_reduce_max(lm, scratch);
    float ls = 0.f;
    for (int t = st + tid; t < en; t += 256) ls += __expf(scores[t] - m);
    float den = block_reduce_sum(ls, scratch);
    float inv = 1.f / den;
    for (int t = st + tid; t < en; t += 256) wgt[t - st] = __expf(scores[t] - m) * inv;
    __syncthreads();
    int len = en - st;
    const float* f0 = feats + (size_t)tid * TP_ + st;
    const float* f1 = f0 + (size_t)256 * TP_;
    const float* f2 = f0 + (size_t)512 * TP_;
    float a0 = 0.f, a1 = 0.f, a2 = 0.f;
    for (int t = 0; t < len; t++) {
        float wv = wgt[t];
        a0 = fmaf(wv, f0[t], a0);
        a1 = fmaf(wv, f1[t], a1);
        a2 = fmaf(wv, f2[t], a2);
    }
    tout[tid] = a0 + pos_emb[s * DMODEL + tid];
    tout[tid + 256] = a1 + pos_emb[s * DMODEL + tid + 256];
    tout[tid + 512] = a2 + pos_emb[s * DMODEL + tid + 512];
}

// ---------------- generic NT linear: C[n][m] = X[n][k] . W[m][k] + b[m] ----------------
template <int RELU>
__global__ __launch_bounds__(256) void linear_nt(const float* __restrict__ X,
                                                 const float* __restrict__ W,
                                                 const float* __restrict__ bias,
                                                 float* __restrict__ C,
                                                 int M, int K) {
    __shared__ float sX[16][68];
    __shared__ float sW[16][68];
    const int n0 = blockIdx.x * 64;
    const int m0 = blockIdx.y * 64;
    const int tid = threadIdx.x;
    const int tx = tid & 15;
    const int ty = tid >> 4;
    const int lrow = tid >> 2;
    const int lcg = (tid & 3) * 4;
    const float* Xp = X + (size_t)(n0 + lrow) * K + lcg;
    int wrow = m0 + lrow; if (wrow > M - 1) wrow = M - 1;
    const float* Wp = W + (size_t)wrow * K + lcg;
    float acc[4][4];
#pragma unroll
    for (int i = 0; i < 4; i++)
#pragma unroll
        for (int l = 0; l < 4; l++) acc[i][l] = 0.f;

    for (int kc = 0; kc < K; kc += 16) {
        float4 xv = *(const float4*)(Xp + kc);
        float4 wv = *(const float4*)(Wp + kc);
        sX[lcg + 0][lrow] = xv.x; sX[lcg + 1][lrow] = xv.y;
        sX[lcg + 2][lrow] = xv.z; sX[lcg + 3][lrow] = xv.w;
        sW[lcg + 0][lrow] = wv.x; sW[lcg + 1][lrow] = wv.y;
        sW[lcg + 2][lrow] = wv.z; sW[lcg + 3][lrow] = wv.w;
        __syncthreads();
#pragma unroll
        for (int j = 0; j < 16; j++) {
            const float4 av = *(const float4*)&sX[j][ty * 4];
            const float4 bv = *(const float4*)&sW[j][tx * 4];
            const float aa[4] = {av.x, av.y, av.z, av.w};
            const float bb[4] = {bv.x, bv.y, bv.z, bv.w};
#pragma unroll
            for (int i = 0; i < 4; i++)
#pragma unroll
                for (int l = 0; l < 4; l++) acc[i][l] = fmaf(aa[i], bb[l], acc[i][l]);
        }
        __syncthreads();
    }
#pragma unroll
    for (int i = 0; i < 4; i++) {
        int n = n0 + ty * 4 + i;
        float* crow = C + (size_t)n * M;
#pragma unroll
        for (int l = 0; l < 4; l++) {
            int m = m0 + tx * 4 + l;
            if (m < M) {
                float vv = acc[i][l] + bias[m];
                if (RELU) vv = fmaxf(vv, 0.f);
                crow[m] = vv;
            }
        }
    }
}

// ---------------- attention (one block per (head, batch)) ----------------
__global__ __launch_bounds__(256) void attn_kernel(const float* __restrict__ qkv,
                                                   const int* __restrict__ n_segs,
                                                   float* __restrict__ o) {
    __shared__ float sK[64][68];
    __shared__ float sV[64][68];
    __shared__ float sS[64][68];
    int h = blockIdx.x, b = blockIdx.y, tid = threadIdx.x;
    int ns = n_segs[b];
    const float* base = qkv + (size_t)b * 64 * 2304 + h * 64;
    for (int idx = tid; idx < 4096; idx += 256) {
        int s_ = idx >> 6, d = idx & 63;
        sK[s_][d] = base[(size_t)s_ * 2304 + 768 + d];
        sV[s_][d] = base[(size_t)s_ * 2304 + 1536 + d];
    }
    __syncthreads();
    int qr = tid >> 2;
    int c0 = (tid & 3) * 16;
    const float* qrow = base + (size_t)qr * 2304;
    float acc[16];
#pragma unroll
    for (int j = 0; j < 16; j++) acc[j] = 0.f;
    for (int d = 0; d < 64; d += 4) {
        float4 qv = *(const float4*)(qrow + d);
#pragma unroll
        for (int j = 0; j < 16; j++) {
            float4 kv = *(const float4*)&sK[c0 + j][d];
            acc[j] += qv.x * kv.x + qv.y * kv.y + qv.z * kv.z + qv.w * kv.w;
        }
    }
#pragma unroll
    for (int j = 0; j < 16; j++) {
        int kc = c0 + j;
        float vv = acc[j] * 0.125f;
        if (kc >= ns) vv = -1e9f;
        sS[qr][kc] = vv;
    }
    __syncthreads();
    if (tid < 64) {
        float m = -1e30f;
#pragma unroll 4
        for (int k = 0; k < 64; k++) m = fmaxf(m, sS[tid][k]);
        float ssum = 0.f;
#pragma unroll 4
        for (int k = 0; k < 64; k++) {
            float e = __expf(sS[tid][k] - m);
            sS[tid][k] = e;
            ssum += e;
        }
        float inv = 1.f / ssum;
#pragma unroll 4
        for (int k = 0; k < 64; k++) sS[tid][k] *= inv;
    }
    __syncthreads();
    float4 oacc[4];
#pragma unroll
    for (int j = 0; j < 4; j++) oacc[j] = make_float4(0.f, 0.f, 0.f, 0.f);
    for (int k = 0; k < 64; k++) {
        float wv = sS[qr][k];
#pragma unroll
        for (int j4 = 0; j4 < 4; j4++) {
            float4 vv = *(const float4*)&sV[k][c0 + j4 * 4];
            oacc[j4].x = fmaf(wv, vv.x, oacc[j4].x);
            oacc[j4].y = fmaf(wv, vv.y, oacc[j4].y);
            oacc[j4].z = fmaf(wv, vv.z, oacc[j4].z);
            oacc[j4].w = fmaf(wv, vv.w, oacc[j4].w);
        }
    }
    float* orow = o + ((size_t)b * 64 + qr) * DMODEL + h * 64 + c0;
#pragma unroll
    for (int j4 = 0; j4 < 4; j4++) *(float4*)(orow + j4 * 4) = oacc[j4];
}

// ---------------- layernorm (+ optional residual), row = token ----------------
__global__ __launch_bounds__(256) void ln_kernel(const float* __restrict__ x,
                                                 const float* __restrict__ r,
                                                 const float* __restrict__ w,
                                                 const float* __restrict__ b,
                                                 float* __restrict__ out) {
    __shared__ float scratch[4];
    int row = blockIdx.x, tid = threadIdx.x;
    const float* xr = x + (size_t)row * DMODEL;
    float v0 = xr[tid], v1 = xr[tid + 256], v2 = xr[tid + 512];
    if (r) {
        const float* rr = r + (size_t)row * DMODEL;
        v0 += rr[tid]; v1 += rr[tid + 256]; v2 += rr[tid + 512];
    }
    float mean = block_reduce_sum(v0 + v1 + v2, scratch) * (1.f / DMODEL);
    float d0 = v0 - mean, d1 = v1 - mean, d2 = v2 - mean;
    float var = block_reduce_sum(d0 * d0 + d1 * d1 + d2 * d2, scratch) * (1.f / DMODEL);
    float inv = rsqrtf(var + 1e-5f);
    float* orow = out + (size_t)row * DMODEL;
    orow[tid] = d0 * inv * w[tid] + b[tid];
    orow[tid + 256] = d1 * inv * w[tid + 256] + b[tid + 256];
    orow[tid + 512] = d2 * inv * w[tid + 512] + b[tid + 512];
}

// ---------------- pad mask output ----------------
__global__ void mask_kernel(const int* __restrict__ n_segs, float* __restrict__ mout) {
    int i = threadIdx.x;
    int b = i >> 6, s = i & 63;
    mout[i] = (s >= n_segs[b]) ? 1.0f : 0.0f;
}

// ---------------- host ----------------
extern "C" void kernel_launch(void* const* d_in, const int* in_sizes, int n_in,
                              void* d_out, int out_size, void* d_ws, size_t ws_size,
                              hipStream_t stream) {
    const float* x = (const float*)d_in[0];
    const int* seg_bounds = (const int*)d_in[1];
    const int* n_segs = (const int*)d_in[2];
    const float* cw[7], * cb[7];
    for (int i = 0; i < 7; i++) { cw[i] = (const float*)d_in[3 + 2 * i]; cb[i] = (const float*)d_in[4 + 2 * i]; }
    const float* attn_v = (const float*)d_in[17];
    const float* pos_emb = (const float*)d_in[18];
    const float* in_w = (const float*)d_in[19];
    const float* in_b = (const float*)d_in[20];
    const float* out_w = (const float*)d_in[21];
    const float* out_b = (const float*)d_in[22];
    const float* ff1_w = (const float*)d_in[23];
    const float* ff1_b = (const float*)d_in[24];
    const float* ff2_w = (const float*)d_in[25];
    const float* ff2_b = (const float*)d_in[26];
    const float* ln1_w = (const float*)d_in[27];
    const float* ln1_b = (const float*)d_in[28];
    const float* ln2_w = (const float*)d_in[29];
    const float* ln2_b = (const float*)d_in[30];
    const float* fln_w = (const float*)d_in[31];
    const float* fln_b = (const float*)d_in[32];
    const float* proj_w = (const float*)d_in[33];
    const float* proj_b = (const float*)d_in[34];

    // diagnostic + output piece that needs no workspace: always runs
    mask_kernel<<<1, 256, 0, stream>>>(n_segs, (float*)d_out + 256 * NCLS);

    // workspace layout (per-batch conv ping-pong): ~57 MB total
    size_t off = 0;
    auto alloc = [&](size_t bytes) {
        void* p = (char*)d_ws + off;
        off += (bytes + 255) & ~(size_t)255;
        return p;
    };
    float* bufP = (float*)alloc((size_t)512 * 15999 * 4);   // 32.8 MB
    float* bufQ = (float*)alloc((size_t)512 * 7999 * 4);    // 16.4 MB
    float* scoresB = (float*)alloc((size_t)TP_ * 4);
    float* tokens = (float*)alloc((size_t)256 * DMODEL * 4);
    float* qkv = (float*)alloc((size_t)256 * 2304 * 4);
    float* oall = (float*)alloc((size_t)256 * DMODEL * 4);
    float* ffh = (float*)alloc((size_t)256 * FFDIM * 4);
    float* tmp = (float*)alloc((size_t)256 * DMODEL * 4);
    float* ybuf = (float*)alloc((size_t)256 * DMODEL * 4);
    if (off > ws_size) return;  // workspace too small (mask still written as diagnostic)

    // ---- conv stack + pooling, one batch at a time ----
    for (int b = 0; b < BATCH; b++) {
        const float* xb = x + (size_t)b * TIN0;
        conv01_fused<<<dim3(8, 250), 256, 0, stream>>>(xb, cw[0], cb[0], cw[1], cb[1], bufP);
        conv_gemm<3, 512><<<dim3(8, 125), 256, 0, stream>>>(bufP, cw[2], cb[2], bufQ, 512, 15999, 7999);
        conv_gemm<3, 512><<<dim3(8, 63), 256, 0, stream>>>(bufQ, cw[3], cb[3], bufP, 512, 7999, 3999);
        conv_gemm<2, 512><<<dim3(8, 32), 256, 0, stream>>>(bufP, cw[4], cb[4], bufQ, 512, 3999, 1999);
        conv_gemm<2, 512><<<dim3(8, 16), 256, 0, stream>>>(bufQ, cw[5], cb[5], bufP, 512, 1999, 999);
        conv_gemm<2, 512><<<dim3(12, 8), 256, 0, stream>>>(bufP, cw[6], cb[6], bufQ, 768, 999, 499);
        // feats = bufQ [768][499]
        scores_kernel<<<2, 256, 0, stream>>>(bufQ, attn_v, scoresB);
        pool_kernel<<<SMAX_, 256, 0, stream>>>(bufQ, scoresB, seg_bounds + b * (SMAX_ + 1),
                                               n_segs, b, pos_emb,
                                               tokens + (size_t)b * SMAX_ * DMODEL);
    }

    // ---- transformer ----
    for (int l = 0; l < NLAYER; l++) {
        const float* iw = in_w + (size_t)l * 2304 * DMODEL;
        const float* ib = in_b + (size_t)l * 2304;
        const float* ow = out_w + (size_t)l * DMODEL * DMODEL;
        const float* ob = out_b + (size_t)l * DMODEL;
        const float* f1w = ff1_w + (size_t)l * FFDIM * DMODEL;
        const float* f1b = ff1_b + (size_t)l * FFDIM;
        const float* f2w = ff2_w + (size_t)l * DMODEL * FFDIM;
        const float* f2b = ff2_b + (size_t)l * DMODEL;
        linear_nt<0><<<dim3(4, 36), 256, 0, stream>>>(tokens, iw, ib, qkv, 2304, DMODEL);
        attn_kernel<<<dim3(NHEAD, 4), 256, 0, stream>>>(qkv, n_segs, oall);
        linear_nt<0><<<dim3(4, 12), 256, 0, stream>>>(oall, ow, ob, tmp, DMODEL, DMODEL);
        ln_kernel<<<256, 256, 0, stream>>>(tokens, tmp, ln1_w + l * DMODEL, ln1_b + l * DMODEL, tokens);
        linear_nt<1><<<dim3(4, 32), 256, 0, stream>>>(tokens, f1w, f1b, ffh, FFDIM, DMODEL);
        linear_nt<0><<<dim3(4, 12), 256, 0, stream>>>(ffh, f2w, f2b, tmp, DMODEL, FFDIM);
        ln_kernel<<<256, 256, 0, stream>>>(tokens, tmp, ln2_w + l * DMODEL, ln2_b + l * DMODEL, tokens);
    }

    // ---- head ----
    ln_kernel<<<256, 256, 0, stream>>>(tokens, nullptr, fln_w, fln_b, ybuf);
    linear_nt<0><<<dim3(4, 2), 256, 0, stream>>>(ybuf, proj_w, proj_b, (float*)d_out, NCLS, DMODEL);
}

// Round 3
// 4504.530 us; speedup vs baseline: 2.3081x; 2.3081x over previous
//
#include <hip/hip_runtime.h>
#include <hip/hip_bf16.h>

// ---------------- constants ----------------
#define BATCH 4
#define TIN0 160000
#define DMODEL 768
#define NLAYER 12
#define FFDIM 2048
#define NCLS 100
#define SMAX_ 64
#define TP_ 499

typedef __attribute__((ext_vector_type(8))) short short8;
typedef __attribute__((ext_vector_type(4))) float f32x4;

__device__ inline ushort f2b(float f) { __hip_bfloat16 h = __float2bfloat16(f); return *(ushort*)&h; }
__device__ inline float b2f(ushort u) { __hip_bfloat16 h = *(__hip_bfloat16*)&u; return __bfloat162float(h); }

__device__ inline void gl_lds16(const ushort* g, ushort* l) {
    __builtin_amdgcn_global_load_lds((const __attribute__((address_space(1))) unsigned int*)g,
                                     (__attribute__((address_space(3))) unsigned int*)l, 16, 0, 0);
}

// ---------------- reduction helpers ----------------
__device__ inline float wave_reduce_sum(float v) {
#pragma unroll
    for (int off = 32; off > 0; off >>= 1) v += __shfl_down(v, off, 64);
    return v;
}
__device__ inline float wave_reduce_max(float v) {
#pragma unroll
    for (int off = 32; off > 0; off >>= 1) v = fmaxf(v, __shfl_down(v, off, 64));
    return v;
}
__device__ inline float block_reduce_sum(float v, float* scratch) {
    v = wave_reduce_sum(v);
    int wid = threadIdx.x >> 6;
    if ((threadIdx.x & 63) == 0) scratch[wid] = v;
    __syncthreads();
    float r = scratch[0] + scratch[1] + scratch[2] + scratch[3];
    __syncthreads();
    return r;
}
__device__ inline float block_reduce_max(float v, float* scratch) {
    v = wave_reduce_max(v);
    int wid = threadIdx.x >> 6;
    if ((threadIdx.x & 63) == 0) scratch[wid] = v;
    __syncthreads();
    float r = fmaxf(fmaxf(scratch[0], scratch[1]), fmaxf(scratch[2], scratch[3]));
    __syncthreads();
    return r;
}

// =================================================================
// Generic MFMA implicit-GEMM conv / GEMM.
// A (activations) time-major [Tin][Cin] bf16; Wc [Cout][K] bf16 with K
// ordered kw-major (k = kw*Cin + ic); out [Tout][Cout].
// out[t][oc] = act( bias[oc] + sum_k Wc[oc][k] * A[STRIDE*t+kw][ic] )
// Tile: 128 t x 128 oc, 256 threads (4 waves), BK=32.
// LDS slots XOR-swizzled so both staging (lane-contiguous) and
// ds_read_b128 frag reads (2-way, free) are conflict-free.
// FUSE0: A is generated on the fly as conv0(x) (Cin=1,K=10,stride5)+relu.
// =================================================================
template <int KW, int STRIDE, int FUSE0, int RELU, int OBF>
__global__ __launch_bounds__(256) void conv_mfma(
    const ushort* __restrict__ A,
    const float* __restrict__ x,     // FUSE0 only
    const float* __restrict__ w0,    // FUSE0 only [512][10]
    const float* __restrict__ b0,    // FUSE0 only [512]
    const ushort* __restrict__ Wc,
    const float* __restrict__ bias,
    void* __restrict__ outv,
    int Cin, int Cout, int Tout,
    long aStride, long oStride) {
    const int K = KW * Cin;
    const int nCh = K >> 5;
    const int CPK = Cin >> 5;
    const int t0 = blockIdx.x * 128;
    const int oc0 = blockIdx.y * 128;
    const int b = blockIdx.z;
    const ushort* Ab = A + (size_t)b * aStride;

    __shared__ ushort sA[4096];  // 128 rows x 32 bf16
    __shared__ ushort sB[4096];

    const int tid = threadIdx.x;
    const int lane = tid & 63;
    const int wv = tid >> 6;
    // staging: this thread's (row-in-64, swizzled k-group)
    const int rsub = lane >> 2;                       // row within 16-row chunk
    const int kgW = (lane & 3) ^ ((lane >> 3) & 3);   // data k-group for this slot
    // frag-read addressing
    const int mrow = lane & 15;
    const int kq = lane >> 4;
    const int slot8 = (mrow * 4 + (kq ^ ((mrow >> 1) & 3))) * 8;  // shorts

    f32x4 acc[2][8];
#pragma unroll
    for (int s = 0; s < 2; s++)
#pragma unroll
        for (int n = 0; n < 8; n++) acc[s][n] = (f32x4){0.f, 0.f, 0.f, 0.f};

    // FUSE0: preload per-thread x windows (two staged rows -> 2x20 floats)
    float xr[FUSE0 ? 2 : 1][FUSE0 ? 20 : 1];
    if (FUSE0) {
#pragma unroll
        for (int j = 0; j < 2; j++) {
            int t = t0 + j * 64 + wv * 16 + rsub;
            if (t > Tout - 1) t = Tout - 1;
            const float* xp = x + 10 * t;
#pragma unroll
            for (int q = 0; q < 10; q++) {
                float2 v = *(const float2*)(xp + 2 * q);
                xr[j][2 * q] = v.x; xr[j][2 * q + 1] = v.y;
            }
        }
    }

    for (int c = 0; c < nCh; c++) {
        const int kw = (KW == 1) ? 0 : (c / CPK);
        const int icc = (c - kw * CPK) << 5;
        // ---- stage A ----
#pragma unroll
        for (int j = 0; j < 2; j++) {
            int t = t0 + j * 64 + wv * 16 + rsub;
            if (t > Tout - 1) t = Tout - 1;
            if (FUSE0) {
                short8 vals;
#pragma unroll
                for (int e = 0; e < 8; e++) {
                    int ic = icc + kgW * 8 + e;
                    const float* wp = w0 + ic * 10;
                    float a = b0[ic];
                    if (kw == 0) {
#pragma unroll
                        for (int q = 0; q < 10; q++) a = fmaf(xr[j][q], wp[q], a);
                    } else if (kw == 1) {
#pragma unroll
                        for (int q = 0; q < 10; q++) a = fmaf(xr[j][5 + q], wp[q], a);
                    } else {
#pragma unroll
                        for (int q = 0; q < 10; q++) a = fmaf(xr[j][10 + q], wp[q], a);
                    }
                    a = fmaxf(a, 0.f);
                    vals[e] = (short)f2b(a);
                }
                *(short8*)&sA[(j * 64 + wv * 16) * 32 + lane * 8] = vals;
            } else {
                int u = STRIDE * t + kw;
                gl_lds16(Ab + (size_t)u * Cin + icc + kgW * 8, &sA[(j * 64 + wv * 16) * 32]);
            }
        }
        // ---- stage B (weights) ----
#pragma unroll
        for (int j = 0; j < 2; j++) {
            int rowb = oc0 + j * 64 + wv * 16 + rsub;
            if (rowb > Cout - 1) rowb = Cout - 1;
            gl_lds16(Wc + (size_t)rowb * K + c * 32 + kgW * 8, &sB[(j * 64 + wv * 16) * 32]);
        }
        __syncthreads();
        // ---- MFMA ----
        short8 a0 = *(const short8*)&sA[(wv * 32 + 0) * 32 + slot8];
        short8 a1 = *(const short8*)&sA[(wv * 32 + 16) * 32 + slot8];
#pragma unroll
        for (int n = 0; n < 8; n++) {
            short8 bf = *(const short8*)&sB[(n * 16) * 32 + slot8];
            acc[0][n] = __builtin_amdgcn_mfma_f32_16x16x32_bf16(a0, bf, acc[0][n], 0, 0, 0);
            acc[1][n] = __builtin_amdgcn_mfma_f32_16x16x32_bf16(a1, bf, acc[1][n], 0, 0, 0);
        }
        __syncthreads();
    }

    // ---- epilogue ----
    float* outf = (float*)outv + (size_t)b * oStride;
    ushort* outh = (ushort*)outv + (size_t)b * oStride;
    float bz[8];
#pragma unroll
    for (int n = 0; n < 8; n++) {
        int oc = oc0 + n * 16 + mrow;
        bz[n] = (oc < Cout) ? bias[oc] : 0.f;
    }
#pragma unroll
    for (int s = 0; s < 2; s++) {
        int tb = t0 + wv * 32 + s * 16 + kq * 4;
#pragma unroll
        for (int n = 0; n < 8; n++) {
            int oc = oc0 + n * 16 + mrow;
            if (oc >= Cout) continue;
#pragma unroll
            for (int r = 0; r < 4; r++) {
                int t = tb + r;
                if (t < Tout) {
                    float v = acc[s][n][r] + bz[n];
                    if (RELU) v = fmaxf(v, 0.f);
                    if (OBF) outh[(size_t)t * Cout + oc] = f2b(v);
                    else outf[(size_t)t * Cout + oc] = v;
                }
            }
        }
    }
}

// ---------------- conv-weight permute+cast: w[oc][ic][kw] -> Wc[oc][kw*Cin+ic] bf16 ----------------
__global__ __launch_bounds__(256) void convw_kernel(
    const float* __restrict__ w1, const float* __restrict__ w2, const float* __restrict__ w3,
    const float* __restrict__ w4, const float* __restrict__ w5, const float* __restrict__ w6,
    const float* __restrict__ wproj, ushort* __restrict__ dst, ushort* __restrict__ dproj) {
    const int z = blockIdx.y;
    const int COUTS[7] = {512, 512, 512, 512, 512, 768, NCLS};
    const int CINS[7] = {512, 512, 512, 512, 512, 512, DMODEL};
    const int KWS[7] = {3, 3, 3, 2, 2, 2, 1};
    const long OFFS[7] = {0, 786432, 1572864, 2359296, 2883584, 3407872, 0};
    const float* srcs[7] = {w1, w2, w3, w4, w5, w6, wproj};
    const float* src = srcs[z];
    ushort* d = (z == 6) ? dproj : dst + OFFS[z];
    const int Cin = CINS[z], Kw = KWS[z];
    const int K = Cin * Kw;
    const long n = (long)COUTS[z] * K;
    for (long o = blockIdx.x * 256 + threadIdx.x; o < n; o += (long)gridDim.x * 256) {
        long oc = o / K;
        int rem = (int)(o - oc * K);
        int kw = rem / Cin, ic = rem - kw * Cin;
        d[o] = f2b(src[(oc * Cin + ic) * Kw + kw]);
    }
}

// ---------------- plain fp32 -> bf16 cast ----------------
__global__ __launch_bounds__(256) void wcast_kernel(const float* __restrict__ s, ushort* __restrict__ d, long n) {
    for (long i = (long)blockIdx.x * 2048 + threadIdx.x; i < n; i += (long)gridDim.x * 2048) {
#pragma unroll
        for (int j = 0; j < 8; j++) {
            long k = i + (long)j * 256;
            if (k < n) d[k] = f2b(s[k]);
        }
    }
}

// ---------------- scores: feats[b][t][:] . attn_v ----------------
__global__ __launch_bounds__(256) void scores_kernel(const ushort* __restrict__ feats,
                                                     const float* __restrict__ v,
                                                     float* __restrict__ scores) {
    int b = blockIdx.y;
    int t = blockIdx.x * 4 + (threadIdx.x >> 6);
    if (t >= TP_) return;
    int lane = threadIdx.x & 63;
    const ushort* f = feats + ((size_t)b * TP_ + t) * DMODEL + lane * 12;
    float acc = 0.f;
#pragma unroll
    for (int q = 0; q < 12; q++) acc = fmaf(b2f(f[q]), v[lane * 12 + q], acc);
    acc = wave_reduce_sum(acc);
    if (lane == 0) scores[b * TP_ + t] = acc;
}

// ---------------- per-segment softmax pooling + pos_emb ----------------
__global__ __launch_bounds__(256) void pool_kernel(const ushort* __restrict__ featsAll,
                                                   const float* __restrict__ scoresAll,
                                                   const int* __restrict__ seg_bounds,
                                                   const int* __restrict__ n_segs,
                                                   const float* __restrict__ pos_emb,
                                                   float* __restrict__ tokens,
                                                   ushort* __restrict__ tokens_bf) {
    __shared__ float scratch[4];
    __shared__ float wgt[512];
    int s = blockIdx.x, b = blockIdx.y, tid = threadIdx.x;
    float* tout = tokens + ((size_t)b * SMAX_ + s) * DMODEL;
    ushort* tbf = tokens_bf + ((size_t)b * SMAX_ + s) * DMODEL;
    int ns = n_segs[b];
    if (s >= ns) {
        for (int c = tid; c < DMODEL; c += 256) {
            float v = pos_emb[s * DMODEL + c];
            tout[c] = v; tbf[c] = f2b(v);
        }
        return;
    }
    const float* sc = scoresAll + b * TP_;
    int b0 = seg_bounds[b * (SMAX_ + 1) + s];
    int b1 = seg_bounds[b * (SMAX_ + 1) + s + 1];
    int st = min(max(b0, 0), TP_ - 1);
    int en = max(st + 1, min(max(b1, 0), TP_));
    float lm = -1e30f;
    for (int t = st + tid; t < en; t += 256) lm = fmaxf(lm, sc[t]);
    float m = block_reduce_max(lm, scratch);
    float ls = 0.f;
    for (int t = st + tid; t < en; t += 256) ls += __expf(sc[t] - m);
    float den = block_reduce_sum(ls, scratch);
    float inv = 1.f / den;
    for (int t = st + tid; t < en; t += 256) wgt[t - st] = __expf(sc[t] - m) * inv;
    __syncthreads();
    int len = en - st;
    const ushort* f = featsAll + ((size_t)b * TP_ + st) * DMODEL;
    float a0 = 0.f, a1 = 0.f, a2 = 0.f;
    for (int t = 0; t < len; t++) {
        float wv = wgt[t];
        const ushort* fr = f + (size_t)t * DMODEL;
        a0 = fmaf(wv, b2f(fr[tid]), a0);
        a1 = fmaf(wv, b2f(fr[tid + 256]), a1);
        a2 = fmaf(wv, b2f(fr[tid + 512]), a2);
    }
    float v0 = a0 + pos_emb[s * DMODEL + tid];
    float v1 = a1 + pos_emb[s * DMODEL + tid + 256];
    float v2 = a2 + pos_emb[s * DMODEL + tid + 512];
    tout[tid] = v0; tout[tid + 256] = v1; tout[tid + 512] = v2;
    tbf[tid] = f2b(v0); tbf[tid + 256] = f2b(v1); tbf[tid + 512] = f2b(v2);
}

// ---------------- attention (one block per (head, batch)), fp32 in, bf16 out ----------------
__global__ __launch_bounds__(256) void attn_kernel(const float* __restrict__ qkv,
                                                   const int* __restrict__ n_segs,
                                                   ushort* __restrict__ o) {
    __shared__ float sK[64][68];
    __shared__ float sV[64][68];
    __shared__ float sS[64][68];
    int h = blockIdx.x, b = blockIdx.y, tid = threadIdx.x;
    int ns = n_segs[b];
    const float* base = qkv + (size_t)b * 64 * 2304 + h * 64;
    for (int idx = tid; idx < 4096; idx += 256) {
        int s_ = idx >> 6, d = idx & 63;
        sK[s_][d] = base[(size_t)s_ * 2304 + 768 + d];
        sV[s_][d] = base[(size_t)s_ * 2304 + 1536 + d];
    }
    __syncthreads();
    int qr = tid >> 2;
    int c0 = (tid & 3) * 16;
    const float* qrow = base + (size_t)qr * 2304;
    float acc[16];
#pragma unroll
    for (int j = 0; j < 16; j++) acc[j] = 0.f;
    for (int d = 0; d < 64; d += 4) {
        float4 qv = *(const float4*)(qrow + d);
#pragma unroll
        for (int j = 0; j < 16; j++) {
            float4 kv = *(const float4*)&sK[c0 + j][d];
            acc[j] += qv.x * kv.x + qv.y * kv.y + qv.z * kv.z + qv.w * kv.w;
        }
    }
#pragma unroll
    for (int j = 0; j < 16; j++) {
        int kc = c0 + j;
        float vv = acc[j] * 0.125f;
        if (kc >= ns) vv = -1e9f;
        sS[qr][kc] = vv;
    }
    __syncthreads();
    if (tid < 64) {
        float m = -1e30f;
#pragma unroll 4
        for (int k = 0; k < 64; k++) m = fmaxf(m, sS[tid][k]);
        float ssum = 0.f;
#pragma unroll 4
        for (int k = 0; k < 64; k++) {
            float e = __expf(sS[tid][k] - m);
            sS[tid][k] = e;
            ssum += e;
        }
        float inv = 1.f / ssum;
#pragma unroll 4
        for (int k = 0; k < 64; k++) sS[tid][k] *= inv;
    }
    __syncthreads();
    float4 oacc[4];
#pragma unroll
    for (int j = 0; j < 4; j++) oacc[j] = make_float4(0.f, 0.f, 0.f, 0.f);
    for (int k = 0; k < 64; k++) {
        float wv = sS[qr][k];
#pragma unroll
        for (int j4 = 0; j4 < 4; j4++) {
            float4 vv = *(const float4*)&sV[k][c0 + j4 * 4];
            oacc[j4].x = fmaf(wv, vv.x, oacc[j4].x);
            oacc[j4].y = fmaf(wv, vv.y, oacc[j4].y);
            oacc[j4].z = fmaf(wv, vv.z, oacc[j4].z);
            oacc[j4].w = fmaf(wv, vv.w, oacc[j4].w);
        }
    }
    ushort* orow = o + ((size_t)b * 64 + qr) * DMODEL + h * 64 + c0;
#pragma unroll
    for (int j4 = 0; j4 < 4; j4++) {
        orow[j4 * 4 + 0] = f2b(oacc[j4].x);
        orow[j4 * 4 + 1] = f2b(oacc[j4].y);
        orow[j4 * 4 + 2] = f2b(oacc[j4].z);
        orow[j4 * 4 + 3] = f2b(oacc[j4].w);
    }
}

// ---------------- layernorm (+ optional residual), fp32 out + optional bf16 out ----------------
__global__ __launch_bounds__(256) void ln_kernel(const float* __restrict__ x,
                                                 const float* __restrict__ r,
                                                 const float* __restrict__ w,
                                                 const float* __restrict__ b,
                                                 float* __restrict__ out,
                                                 ushort* __restrict__ outbf) {
    __shared__ float scratch[4];
    int row = blockIdx.x, tid = threadIdx.x;
    const float* xr = x + (size_t)row * DMODEL;
    float v0 = xr[tid], v1 = xr[tid + 256], v2 = xr[tid + 512];
    if (r) {
        const float* rr = r + (size_t)row * DMODEL;
        v0 += rr[tid]; v1 += rr[tid + 256]; v2 += rr[tid + 512];
    }
    float mean = block_reduce_sum(v0 + v1 + v2, scratch) * (1.f / DMODEL);
    float d0 = v0 - mean, d1 = v1 - mean, d2 = v2 - mean;
    float var = block_reduce_sum(d0 * d0 + d1 * d1 + d2 * d2, scratch) * (1.f / DMODEL);
    float inv = rsqrtf(var + 1e-5f);
    float o0 = d0 * inv * w[tid] + b[tid];
    float o1 = d1 * inv * w[tid + 256] + b[tid + 256];
    float o2 = d2 * inv * w[tid + 512] + b[tid + 512];
    float* orow = out + (size_t)row * DMODEL;
    orow[tid] = o0; orow[tid + 256] = o1; orow[tid + 512] = o2;
    if (outbf) {
        ushort* obf = outbf + (size_t)row * DMODEL;
        obf[tid] = f2b(o0); obf[tid + 256] = f2b(o1); obf[tid + 512] = f2b(o2);
    }
}

// ---------------- pad mask output ----------------
__global__ void mask_kernel(const int* __restrict__ n_segs, float* __restrict__ mout) {
    int i = threadIdx.x;
    int b = i >> 6, s = i & 63;
    mout[i] = (s >= n_segs[b]) ? 1.0f : 0.0f;
}

// ---------------- host ----------------
extern "C" void kernel_launch(void* const* d_in, const int* in_sizes, int n_in,
                              void* d_out, int out_size, void* d_ws, size_t ws_size,
                              hipStream_t stream) {
    const float* x = (const float*)d_in[0];
    const int* seg_bounds = (const int*)d_in[1];
    const int* n_segs = (const int*)d_in[2];
    const float* cw[7], * cb[7];
    for (int i = 0; i < 7; i++) { cw[i] = (const float*)d_in[3 + 2 * i]; cb[i] = (const float*)d_in[4 + 2 * i]; }
    const float* attn_v = (const float*)d_in[17];
    const float* pos_emb = (const float*)d_in[18];
    const float* in_w = (const float*)d_in[19];
    const float* in_b = (const float*)d_in[20];
    const float* out_w = (const float*)d_in[21];
    const float* out_b = (const float*)d_in[22];
    const float* ff1_w = (const float*)d_in[23];
    const float* ff1_b = (const float*)d_in[24];
    const float* ff2_w = (const float*)d_in[25];
    const float* ff2_b = (const float*)d_in[26];
    const float* ln1_w = (const float*)d_in[27];
    const float* ln1_b = (const float*)d_in[28];
    const float* ln2_w = (const float*)d_in[29];
    const float* ln2_b = (const float*)d_in[30];
    const float* fln_w = (const float*)d_in[31];
    const float* fln_b = (const float*)d_in[32];
    const float* proj_w = (const float*)d_in[33];
    const float* proj_b = (const float*)d_in[34];

    mask_kernel<<<1, 256, 0, stream>>>(n_segs, (float*)d_out + 256 * NCLS);

    size_t off = 0;
    auto alloc = [&](size_t bytes) {
        void* p = (char*)d_ws + off;
        off += (bytes + 255) & ~(size_t)255;
        return p;
    };
    ushort* wbc = (ushort*)alloc(4194304ULL * 2);        // conv1-6 weights bf16, kw-major
    ushort* wbproj = (ushort*)alloc(76800ULL * 2);
    ushort* out1 = (ushort*)alloc((size_t)15999 * 512 * 2);   // per-batch conv1 out
    ushort* out2b = (ushort*)alloc((size_t)7999 * 512 * 2);   // per-batch conv2 out
    ushort* out4 = (ushort*)alloc((size_t)4 * 1999 * 512 * 2);
    float* scores = (float*)alloc((size_t)4 * TP_ * 4);
    float* tokens = (float*)alloc((size_t)256 * DMODEL * 4);
    ushort* tokens_bf = (ushort*)alloc((size_t)256 * DMODEL * 2);
    float* qkv = (float*)alloc((size_t)256 * 2304 * 4);
    ushort* oall_bf = (ushort*)alloc((size_t)256 * DMODEL * 2);
    float* tmp = (float*)alloc((size_t)256 * DMODEL * 4);
    ushort* ffh_bf = (ushort*)alloc((size_t)256 * FFDIM * 2);
    float* ybuf = (float*)alloc((size_t)256 * DMODEL * 4);
    ushort* ybf = (ushort*)alloc((size_t)256 * DMODEL * 2);
    ushort* wbg = (ushort*)alloc((size_t)2304 * 768 * 2);     // rotating transformer weight buffer
    if (off > ws_size) return;  // diagnostic bail (mask already written)

    // aliases (lifetimes disjoint, see sequence)
    ushort* out3b = out1 + (size_t)12000 * 512;   // conv3 out (tail of out1, after conv2 consumed it)
    ushort* out5 = out2b;                          // conv5 out (out2b dead after conv3 of last batch)
    ushort* feats = out1;                          // conv6 out (out1 dead after conv loop)

    ushort* wc1 = wbc, * wc2 = wbc + 786432, * wc3 = wbc + 1572864,
          * wc4 = wbc + 2359296, * wc5 = wbc + 2883584, * wc6 = wbc + 3407872;

    // ---- weight conversion ----
    convw_kernel<<<dim3(512, 7), 256, 0, stream>>>(cw[1], cw[2], cw[3], cw[4], cw[5], cw[6],
                                                   proj_w, wbc, wbproj);

    // ---- conv stack (bf16 MFMA), convs 1-4 per batch, 5-6 z-batched ----
    for (int b = 0; b < BATCH; b++) {
        const float* xb = x + (size_t)b * TIN0;
        conv_mfma<3, 2, 1, 1, 1><<<dim3(125, 4, 1), 256, 0, stream>>>(
            nullptr, xb, cw[0], cb[0], wc1, cb[1], out1, 512, 512, 15999, 0, 0);
        conv_mfma<3, 2, 0, 1, 1><<<dim3(63, 4, 1), 256, 0, stream>>>(
            out1, nullptr, nullptr, nullptr, wc2, cb[2], out2b, 512, 512, 7999, 0, 0);
        conv_mfma<3, 2, 0, 1, 1><<<dim3(32, 4, 1), 256, 0, stream>>>(
            out2b, nullptr, nullptr, nullptr, wc3, cb[3], out3b, 512, 512, 3999, 0, 0);
        conv_mfma<2, 2, 0, 1, 1><<<dim3(16, 4, 1), 256, 0, stream>>>(
            out3b, nullptr, nullptr, nullptr, wc4, cb[4], out4 + (size_t)b * 1999 * 512,
            512, 512, 1999, 0, 0);
    }
    conv_mfma<2, 2, 0, 1, 1><<<dim3(8, 4, BATCH), 256, 0, stream>>>(
        out4, nullptr, nullptr, nullptr, wc5, cb[5], out5, 512, 512, 999,
        (long)1999 * 512, (long)999 * 512);
    conv_mfma<2, 2, 0, 1, 1><<<dim3(4, 6, BATCH), 256, 0, stream>>>(
        out5, nullptr, nullptr, nullptr, wc6, cb[6], feats, 512, 768, 499,
        (long)999 * 512, (long)499 * 768);

    // ---- pooling ----
    scores_kernel<<<dim3(125, 4), 256, 0, stream>>>(feats, attn_v, scores);
    pool_kernel<<<dim3(SMAX_, 4), 256, 0, stream>>>(feats, scores, seg_bounds, n_segs,
                                                    pos_emb, tokens, tokens_bf);

    // ---- transformer (bf16 MFMA GEMMs, per-layer weight cast) ----
    for (int l = 0; l < NLAYER; l++) {
        const float* iw = in_w + (size_t)l * 2304 * DMODEL;
        const float* ib = in_b + (size_t)l * 2304;
        const float* ow = out_w + (size_t)l * DMODEL * DMODEL;
        const float* ob = out_b + (size_t)l * DMODEL;
        const float* f1w = ff1_w + (size_t)l * FFDIM * DMODEL;
        const float* f1b = ff1_b + (size_t)l * FFDIM;
        const float* f2w = ff2_w + (size_t)l * DMODEL * FFDIM;
        const float* f2b_ = ff2_b + (size_t)l * DMODEL;

        wcast_kernel<<<864, 256, 0, stream>>>(iw, wbg, (long)2304 * 768);
        conv_mfma<1, 1, 0, 0, 0><<<dim3(2, 18, 1), 256, 0, stream>>>(
            tokens_bf, nullptr, nullptr, nullptr, wbg, ib, qkv, 768, 2304, 256, 0, 0);
        attn_kernel<<<dim3(12, 4), 256, 0, stream>>>(qkv, n_segs, oall_bf);
        wcast_kernel<<<288, 256, 0, stream>>>(ow, wbg, (long)768 * 768);
        conv_mfma<1, 1, 0, 0, 0><<<dim3(2, 6, 1), 256, 0, stream>>>(
            oall_bf, nullptr, nullptr, nullptr, wbg, ob, tmp, 768, 768, 256, 0, 0);
        ln_kernel<<<256, 256, 0, stream>>>(tokens, tmp, ln1_w + l * DMODEL, ln1_b + l * DMODEL,
                                           tokens, tokens_bf);
        wcast_kernel<<<768, 256, 0, stream>>>(f1w, wbg, (long)FFDIM * 768);
        conv_mfma<1, 1, 0, 1, 1><<<dim3(2, 16, 1), 256, 0, stream>>>(
            tokens_bf, nullptr, nullptr, nullptr, wbg, f1b, ffh_bf, 768, FFDIM, 256, 0, 0);
        wcast_kernel<<<768, 256, 0, stream>>>(f2w, wbg, (long)768 * FFDIM);
        conv_mfma<1, 1, 0, 0, 0><<<dim3(2, 6, 1), 256, 0, stream>>>(
            ffh_bf, nullptr, nullptr, nullptr, wbg, f2b_, tmp, FFDIM, 768, 256, 0, 0);
        ln_kernel<<<256, 256, 0, stream>>>(tokens, tmp, ln2_w + l * DMODEL, ln2_b + l * DMODEL,
                                           tokens, tokens_bf);
    }

    // ---- head ----
    ln_kernel<<<256, 256, 0, stream>>>(tokens, nullptr, fln_w, fln_b, ybuf, ybf);
    conv_mfma<1, 1, 0, 0, 0><<<dim3(2, 1, 1), 256, 0, stream>>>(
        ybf, nullptr, nullptr, nullptr, wbproj, proj_b, (float*)d_out, 768, NCLS, 256, 0, 0);
}

// Round 4
// 4124.477 us; speedup vs baseline: 2.5208x; 1.0921x over previous
//
#include <hip/hip_runtime.h>
#include <hip/hip_bf16.h>

// ---------------- constants ----------------
#define BATCH 4
#define TIN0 160000
#define DMODEL 768
#define NLAYER 12
#define FFDIM 2048
#define NCLS 100
#define SMAX_ 64
#define TP_ 499

typedef __attribute__((ext_vector_type(8))) short short8;
typedef __attribute__((ext_vector_type(4))) float f32x4;

__device__ inline ushort f2b(float f) { __hip_bfloat16 h = __float2bfloat16(f); return *(ushort*)&h; }
__device__ inline float b2f(ushort u) { __hip_bfloat16 h = *(__hip_bfloat16*)&u; return __bfloat162float(h); }

__device__ inline void gl_lds16(const ushort* g, ushort* l) {
    __builtin_amdgcn_global_load_lds((const __attribute__((address_space(1))) unsigned int*)g,
                                     (__attribute__((address_space(3))) unsigned int*)l, 16, 0, 0);
}

// ---------------- reduction helpers ----------------
__device__ inline float wave_reduce_sum(float v) {
#pragma unroll
    for (int off = 32; off > 0; off >>= 1) v += __shfl_down(v, off, 64);
    return v;
}
__device__ inline float wave_reduce_max(float v) {
#pragma unroll
    for (int off = 32; off > 0; off >>= 1) v = fmaxf(v, __shfl_down(v, off, 64));
    return v;
}
__device__ inline float block_reduce_sum(float v, float* scratch) {
    v = wave_reduce_sum(v);
    int wid = threadIdx.x >> 6;
    if ((threadIdx.x & 63) == 0) scratch[wid] = v;
    __syncthreads();
    float r = scratch[0] + scratch[1] + scratch[2] + scratch[3];
    __syncthreads();
    return r;
}
__device__ inline float block_reduce_max(float v, float* scratch) {
    v = wave_reduce_max(v);
    int wid = threadIdx.x >> 6;
    if ((threadIdx.x & 63) == 0) scratch[wid] = v;
    __syncthreads();
    float r = fmaxf(fmaxf(scratch[0], scratch[1]), fmaxf(scratch[2], scratch[3]));
    __syncthreads();
    return r;
}

// =================================================================
// Generic MFMA implicit-GEMM conv / GEMM.
// A (activations) time-major [.][Cin] bf16; weights [Cout][K] with K
// kw-major (k = kw*Cin + ic); out [Tout][Cout] (row t global).
// out[t][oc] = act( bias[oc] + sum_k W[oc][k] * A[STRIDE*t+kw - uBase][ic] )
// BF32: weights read from Wf (fp32) and converted in-register; else Wc bf16
// via global_load_lds. Tile: 128 t x 128 oc, 256 threads, BK=32,
// XOR-swizzled LDS slots (staging and ds_read_b128 both conflict-free).
// =================================================================
template <int KW, int STRIDE, int RELU, int OBF, int BF32>
__global__ __launch_bounds__(256) void conv_mfma(
    const ushort* __restrict__ A,
    const ushort* __restrict__ Wc,
    const float* __restrict__ Wf,
    const float* __restrict__ bias,
    void* __restrict__ outv,
    int Cin, int Cout, int Tout, int tBase, int uBase,
    long aStride, long oStride) {
    const int K = KW * Cin;
    const int nCh = K >> 5;
    const int CPK = Cin >> 5;
    const int t0 = tBase + blockIdx.x * 128;
    const int oc0 = blockIdx.y * 128;
    const int b = blockIdx.z;
    const ushort* Ab = A + (size_t)b * aStride;

    __shared__ ushort sA[4096];  // 128 rows x 32 bf16
    __shared__ ushort sB[4096];

    const int tid = threadIdx.x;
    const int lane = tid & 63;
    const int wv = tid >> 6;
    const int rsub = lane >> 2;                       // row within 16-row chunk
    const int kgW = (lane & 3) ^ ((lane >> 3) & 3);   // data k-group for this slot
    const int mrow = lane & 15;
    const int kq = lane >> 4;
    const int slot8 = (mrow * 4 + (kq ^ ((mrow >> 1) & 3))) * 8;  // shorts

    f32x4 acc[2][8];
#pragma unroll
    for (int s = 0; s < 2; s++)
#pragma unroll
        for (int n = 0; n < 8; n++) acc[s][n] = (f32x4){0.f, 0.f, 0.f, 0.f};

    for (int c = 0; c < nCh; c++) {
        const int kw = (KW == 1) ? 0 : (c / CPK);
        const int icc = (c - kw * CPK) << 5;
        // ---- stage A ----
#pragma unroll
        for (int j = 0; j < 2; j++) {
            int t = t0 + j * 64 + wv * 16 + rsub;
            if (t > Tout - 1) t = Tout - 1;
            int u = STRIDE * t + kw - uBase;
            gl_lds16(Ab + (size_t)u * Cin + icc + kgW * 8, &sA[(j * 64 + wv * 16) * 32]);
        }
        // ---- stage B (weights) ----
#pragma unroll
        for (int j = 0; j < 2; j++) {
            int rowb = oc0 + j * 64 + wv * 16 + rsub;
            if (rowb > Cout - 1) rowb = Cout - 1;
            if (BF32) {
                const float* wp = Wf + (size_t)rowb * K + c * 32 + kgW * 8;
                float4 w0_ = *(const float4*)wp;
                float4 w1_ = *(const float4*)(wp + 4);
                short8 vals;
                vals[0] = (short)f2b(w0_.x); vals[1] = (short)f2b(w0_.y);
                vals[2] = (short)f2b(w0_.z); vals[3] = (short)f2b(w0_.w);
                vals[4] = (short)f2b(w1_.x); vals[5] = (short)f2b(w1_.y);
                vals[6] = (short)f2b(w1_.z); vals[7] = (short)f2b(w1_.w);
                *(short8*)&sB[(j * 64 + wv * 16) * 32 + lane * 8] = vals;
            } else {
                gl_lds16(Wc + (size_t)rowb * K + c * 32 + kgW * 8, &sB[(j * 64 + wv * 16) * 32]);
            }
        }
        __syncthreads();
        // ---- MFMA ----
        short8 a0 = *(const short8*)&sA[(wv * 32 + 0) * 32 + slot8];
        short8 a1 = *(const short8*)&sA[(wv * 32 + 16) * 32 + slot8];
#pragma unroll
        for (int n = 0; n < 8; n++) {
            short8 bf = *(const short8*)&sB[(n * 16) * 32 + slot8];
            acc[0][n] = __builtin_amdgcn_mfma_f32_16x16x32_bf16(a0, bf, acc[0][n], 0, 0, 0);
            acc[1][n] = __builtin_amdgcn_mfma_f32_16x16x32_bf16(a1, bf, acc[1][n], 0, 0, 0);
        }
        __syncthreads();
    }

    // ---- epilogue ----
    float* outf = (float*)outv + (size_t)b * oStride;
    ushort* outh = (ushort*)outv + (size_t)b * oStride;
    float bz[8];
#pragma unroll
    for (int n = 0; n < 8; n++) {
        int oc = oc0 + n * 16 + mrow;
        bz[n] = (oc < Cout) ? bias[oc] : 0.f;
    }
#pragma unroll
    for (int s = 0; s < 2; s++) {
        int tb = t0 + wv * 32 + s * 16 + kq * 4;
#pragma unroll
        for (int n = 0; n < 8; n++) {
            int oc = oc0 + n * 16 + mrow;
            if (oc >= Cout) continue;
#pragma unroll
            for (int r = 0; r < 4; r++) {
                int t = tb + r;
                if (t < Tout) {
                    float v = acc[s][n][r] + bz[n];
                    if (RELU) v = fmaxf(v, 0.f);
                    if (OBF) outh[(size_t)t * Cout + oc] = f2b(v);
                    else outf[(size_t)t * Cout + oc] = v;
                }
            }
        }
    }
}

// =================================================================
// conv0 as MFMA GEMM: c0[u][ic] = relu(b0[ic] + sum_q x[5u+q]*w0[ic][q])
// A-patch row u: K=10 padded to 32 (zeros). B = w0pad [512][32] bf16.
// Produces rows [uBase, uBase+nU) into c0 [nU][512] bf16.
// =================================================================
__global__ __launch_bounds__(256) void conv0_mfma(const float* __restrict__ x,
                                                  const ushort* __restrict__ w0pad,
                                                  const float* __restrict__ b0,
                                                  ushort* __restrict__ c0,
                                                  int uBase, int nU) {
    __shared__ ushort sA[4096];
    __shared__ ushort sB[4096];
    const int tid = threadIdx.x;
    const int lane = tid & 63;
    const int wv = tid >> 6;
    const int rsub = lane >> 2;
    const int kgW = (lane & 3) ^ ((lane >> 3) & 3);
    const int mrow = lane & 15;
    const int kq = lane >> 4;
    const int slot8 = (mrow * 4 + (kq ^ ((mrow >> 1) & 3))) * 8;
    const int r0 = blockIdx.x * 128;
    const int oc0 = blockIdx.y * 128;

    f32x4 acc[2][8];
#pragma unroll
    for (int s = 0; s < 2; s++)
#pragma unroll
        for (int n = 0; n < 8; n++) acc[s][n] = (f32x4){0.f, 0.f, 0.f, 0.f};

    // ---- stage A (x patches, K padded 10->32) ----
#pragma unroll
    for (int j = 0; j < 2; j++) {
        int r = r0 + j * 64 + wv * 16 + rsub;
        if (r > nU - 1) r = nU - 1;
        const float* xp = x + (size_t)5 * (uBase + r);
        short8 vals = (short8){0, 0, 0, 0, 0, 0, 0, 0};
        if (kgW == 0) {
#pragma unroll
            for (int q = 0; q < 8; q++) vals[q] = (short)f2b(xp[q]);
        } else if (kgW == 1) {
            vals[0] = (short)f2b(xp[8]);
            vals[1] = (short)f2b(xp[9]);
        }
        *(short8*)&sA[(j * 64 + wv * 16) * 32 + lane * 8] = vals;
    }
    // ---- stage B (w0pad) ----
#pragma unroll
    for (int j = 0; j < 2; j++) {
        int rowb = oc0 + j * 64 + wv * 16 + rsub;
        gl_lds16(w0pad + (size_t)rowb * 32 + kgW * 8, &sB[(j * 64 + wv * 16) * 32]);
    }
    __syncthreads();
    short8 a0 = *(const short8*)&sA[(wv * 32 + 0) * 32 + slot8];
    short8 a1 = *(const short8*)&sA[(wv * 32 + 16) * 32 + slot8];
#pragma unroll
    for (int n = 0; n < 8; n++) {
        short8 bf = *(const short8*)&sB[(n * 16) * 32 + slot8];
        acc[0][n] = __builtin_amdgcn_mfma_f32_16x16x32_bf16(a0, bf, acc[0][n], 0, 0, 0);
        acc[1][n] = __builtin_amdgcn_mfma_f32_16x16x32_bf16(a1, bf, acc[1][n], 0, 0, 0);
    }
#pragma unroll
    for (int s = 0; s < 2; s++) {
        int rb = r0 + wv * 32 + s * 16 + kq * 4;
#pragma unroll
        for (int n = 0; n < 8; n++) {
            int oc = oc0 + n * 16 + mrow;
            float bz = b0[oc];
#pragma unroll
            for (int r = 0; r < 4; r++) {
                int rr = rb + r;
                if (rr < nU) c0[(size_t)rr * 512 + oc] = f2b(fmaxf(acc[s][n][r] + bz, 0.f));
            }
        }
    }
}

// ---------------- conv-weight permute+cast: w[oc][ic][kw] -> Wc[oc][kw*Cin+ic] bf16 ----------------
// z=6: w0 [512][1][10] -> w0pad [512][32] (zero-padded)
__global__ __launch_bounds__(256) void convw_kernel(
    const float* __restrict__ w1, const float* __restrict__ w2, const float* __restrict__ w3,
    const float* __restrict__ w4, const float* __restrict__ w5, const float* __restrict__ w6,
    const float* __restrict__ w0, ushort* __restrict__ dst, ushort* __restrict__ dw0) {
    const int z = blockIdx.y;
    const int COUTS[6] = {512, 512, 512, 512, 512, 768};
    const int KWS[6] = {3, 3, 3, 2, 2, 2};
    const long OFFS[6] = {0, 786432, 1572864, 2359296, 2883584, 3407872};
    const float* srcs[6] = {w1, w2, w3, w4, w5, w6};
    if (z == 6) {
        for (int o = blockIdx.x * 256 + threadIdx.x; o < 512 * 32; o += gridDim.x * 256) {
            int oc = o >> 5, q = o & 31;
            dw0[o] = (q < 10) ? f2b(w0[oc * 10 + q]) : (ushort)0;
        }
        return;
    }
    const float* src = srcs[z];
    ushort* d = dst + OFFS[z];
    const int Cin = 512, Kw = KWS[z];
    const int K = Cin * Kw;
    const long n = (long)COUTS[z] * K;
    for (long o = blockIdx.x * 256 + threadIdx.x; o < n; o += (long)gridDim.x * 256) {
        long oc = o / K;
        int rem = (int)(o - oc * K);
        int kw = rem / Cin, ic = rem - kw * Cin;
        d[o] = f2b(src[(oc * Cin + ic) * Kw + kw]);
    }
}

// ---------------- scores: feats[b][t][:] . attn_v ----------------
__global__ __launch_bounds__(256) void scores_kernel(const ushort* __restrict__ feats,
                                                     const float* __restrict__ v,
                                                     float* __restrict__ scores) {
    int b = blockIdx.y;
    int t = blockIdx.x * 4 + (threadIdx.x >> 6);
    if (t >= TP_) return;
    int lane = threadIdx.x & 63;
    const ushort* f = feats + ((size_t)b * TP_ + t) * DMODEL + lane * 12;
    float acc = 0.f;
#pragma unroll
    for (int q = 0; q < 12; q++) acc = fmaf(b2f(f[q]), v[lane * 12 + q], acc);
    acc = wave_reduce_sum(acc);
    if (lane == 0) scores[b * TP_ + t] = acc;
}

// ---------------- per-segment softmax pooling + pos_emb ----------------
__global__ __launch_bounds__(256) void pool_kernel(const ushort* __restrict__ featsAll,
                                                   const float* __restrict__ scoresAll,
                                                   const int* __restrict__ seg_bounds,
                                                   const int* __restrict__ n_segs,
                                                   const float* __restrict__ pos_emb,
                                                   float* __restrict__ tokens,
                                                   ushort* __restrict__ tokens_bf) {
    __shared__ float scratch[4];
    __shared__ float wgt[512];
    int s = blockIdx.x, b = blockIdx.y, tid = threadIdx.x;
    float* tout = tokens + ((size_t)b * SMAX_ + s) * DMODEL;
    ushort* tbf = tokens_bf + ((size_t)b * SMAX_ + s) * DMODEL;
    int ns = n_segs[b];
    if (s >= ns) {
        for (int c = tid; c < DMODEL; c += 256) {
            float v = pos_emb[s * DMODEL + c];
            tout[c] = v; tbf[c] = f2b(v);
        }
        return;
    }
    const float* sc = scoresAll + b * TP_;
    int b0 = seg_bounds[b * (SMAX_ + 1) + s];
    int b1 = seg_bounds[b * (SMAX_ + 1) + s + 1];
    int st = min(max(b0, 0), TP_ - 1);
    int en = max(st + 1, min(max(b1, 0), TP_));
    float lm = -1e30f;
    for (int t = st + tid; t < en; t += 256) lm = fmaxf(lm, sc[t]);
    float m = block_reduce_max(lm, scratch);
    float ls = 0.f;
    for (int t = st + tid; t < en; t += 256) ls += __expf(sc[t] - m);
    float den = block_reduce_sum(ls, scratch);
    float inv = 1.f / den;
    for (int t = st + tid; t < en; t += 256) wgt[t - st] = __expf(sc[t] - m) * inv;
    __syncthreads();
    int len = en - st;
    const ushort* f = featsAll + ((size_t)b * TP_ + st) * DMODEL;
    float a0 = 0.f, a1 = 0.f, a2 = 0.f;
    for (int t = 0; t < len; t++) {
        float wv = wgt[t];
        const ushort* fr = f + (size_t)t * DMODEL;
        a0 = fmaf(wv, b2f(fr[tid]), a0);
        a1 = fmaf(wv, b2f(fr[tid + 256]), a1);
        a2 = fmaf(wv, b2f(fr[tid + 512]), a2);
    }
    float v0 = a0 + pos_emb[s * DMODEL + tid];
    float v1 = a1 + pos_emb[s * DMODEL + tid + 256];
    float v2 = a2 + pos_emb[s * DMODEL + tid + 512];
    tout[tid] = v0; tout[tid + 256] = v1; tout[tid + 512] = v2;
    tbf[tid] = f2b(v0); tbf[tid + 256] = f2b(v1); tbf[tid + 512] = f2b(v2);
}

// ---------------- attention (one block per (head, batch)), fp32 in, bf16 out ----------------
__global__ __launch_bounds__(256) void attn_kernel(const float* __restrict__ qkv,
                                                   const int* __restrict__ n_segs,
                                                   ushort* __restrict__ o) {
    __shared__ float sK[64][68];
    __shared__ float sV[64][68];
    __shared__ float sS[64][68];
    int h = blockIdx.x, b = blockIdx.y, tid = threadIdx.x;
    int ns = n_segs[b];
    const float* base = qkv + (size_t)b * 64 * 2304 + h * 64;
    for (int idx = tid; idx < 4096; idx += 256) {
        int s_ = idx >> 6, d = idx & 63;
        sK[s_][d] = base[(size_t)s_ * 2304 + 768 + d];
        sV[s_][d] = base[(size_t)s_ * 2304 + 1536 + d];
    }
    __syncthreads();
    int qr = tid >> 2;
    int c0 = (tid & 3) * 16;
    const float* qrow = base + (size_t)qr * 2304;
    float acc[16];
#pragma unroll
    for (int j = 0; j < 16; j++) acc[j] = 0.f;
    for (int d = 0; d < 64; d += 4) {
        float4 qv = *(const float4*)(qrow + d);
#pragma unroll
        for (int j = 0; j < 16; j++) {
            float4 kv = *(const float4*)&sK[c0 + j][d];
            acc[j] += qv.x * kv.x + qv.y * kv.y + qv.z * kv.z + qv.w * kv.w;
        }
    }
#pragma unroll
    for (int j = 0; j < 16; j++) {
        int kc = c0 + j;
        float vv = acc[j] * 0.125f;
        if (kc >= ns) vv = -1e9f;
        sS[qr][kc] = vv;
    }
    __syncthreads();
    if (tid < 64) {
        float m = -1e30f;
#pragma unroll 4
        for (int k = 0; k < 64; k++) m = fmaxf(m, sS[tid][k]);
        float ssum = 0.f;
#pragma unroll 4
        for (int k = 0; k < 64; k++) {
            float e = __expf(sS[tid][k] - m);
            sS[tid][k] = e;
            ssum += e;
        }
        float inv = 1.f / ssum;
#pragma unroll 4
        for (int k = 0; k < 64; k++) sS[tid][k] *= inv;
    }
    __syncthreads();
    float4 oacc[4];
#pragma unroll
    for (int j = 0; j < 4; j++) oacc[j] = make_float4(0.f, 0.f, 0.f, 0.f);
    for (int k = 0; k < 64; k++) {
        float wv = sS[qr][k];
#pragma unroll
        for (int j4 = 0; j4 < 4; j4++) {
            float4 vv = *(const float4*)&sV[k][c0 + j4 * 4];
            oacc[j4].x = fmaf(wv, vv.x, oacc[j4].x);
            oacc[j4].y = fmaf(wv, vv.y, oacc[j4].y);
            oacc[j4].z = fmaf(wv, vv.z, oacc[j4].z);
            oacc[j4].w = fmaf(wv, vv.w, oacc[j4].w);
        }
    }
    ushort* orow = o + ((size_t)b * 64 + qr) * DMODEL + h * 64 + c0;
#pragma unroll
    for (int j4 = 0; j4 < 4; j4++) {
        orow[j4 * 4 + 0] = f2b(oacc[j4].x);
        orow[j4 * 4 + 1] = f2b(oacc[j4].y);
        orow[j4 * 4 + 2] = f2b(oacc[j4].z);
        orow[j4 * 4 + 3] = f2b(oacc[j4].w);
    }
}

// ---------------- layernorm (+ optional residual), fp32 out + optional bf16 out ----------------
__global__ __launch_bounds__(256) void ln_kernel(const float* __restrict__ x,
                                                 const float* __restrict__ r,
                                                 const float* __restrict__ w,
                                                 const float* __restrict__ b,
                                                 float* __restrict__ out,
                                                 ushort* __restrict__ outbf) {
    __shared__ float scratch[4];
    int row = blockIdx.x, tid = threadIdx.x;
    const float* xr = x + (size_t)row * DMODEL;
    float v0 = xr[tid], v1 = xr[tid + 256], v2 = xr[tid + 512];
    if (r) {
        const float* rr = r + (size_t)row * DMODEL;
        v0 += rr[tid]; v1 += rr[tid + 256]; v2 += rr[tid + 512];
    }
    float mean = block_reduce_sum(v0 + v1 + v2, scratch) * (1.f / DMODEL);
    float d0 = v0 - mean, d1 = v1 - mean, d2 = v2 - mean;
    float var = block_reduce_sum(d0 * d0 + d1 * d1 + d2 * d2, scratch) * (1.f / DMODEL);
    float inv = rsqrtf(var + 1e-5f);
    float o0 = d0 * inv * w[tid] + b[tid];
    float o1 = d1 * inv * w[tid + 256] + b[tid + 256];
    float o2 = d2 * inv * w[tid + 512] + b[tid + 512];
    float* orow = out + (size_t)row * DMODEL;
    orow[tid] = o0; orow[tid + 256] = o1; orow[tid + 512] = o2;
    if (outbf) {
        ushort* obf = outbf + (size_t)row * DMODEL;
        obf[tid] = f2b(o0); obf[tid + 256] = f2b(o1); obf[tid + 512] = f2b(o2);
    }
}

// ---------------- pad mask output ----------------
__global__ void mask_kernel(const int* __restrict__ n_segs, float* __restrict__ mout) {
    int i = threadIdx.x;
    int b = i >> 6, s = i & 63;
    mout[i] = (s >= n_segs[b]) ? 1.0f : 0.0f;
}

// ---------------- host ----------------
extern "C" void kernel_launch(void* const* d_in, const int* in_sizes, int n_in,
                              void* d_out, int out_size, void* d_ws, size_t ws_size,
                              hipStream_t stream) {
    const float* x = (const float*)d_in[0];
    const int* seg_bounds = (const int*)d_in[1];
    const int* n_segs = (const int*)d_in[2];
    const float* cw[7], * cb[7];
    for (int i = 0; i < 7; i++) { cw[i] = (const float*)d_in[3 + 2 * i]; cb[i] = (const float*)d_in[4 + 2 * i]; }
    const float* attn_v = (const float*)d_in[17];
    const float* pos_emb = (const float*)d_in[18];
    const float* in_w = (const float*)d_in[19];
    const float* in_b = (const float*)d_in[20];
    const float* out_w = (const float*)d_in[21];
    const float* out_b = (const float*)d_in[22];
    const float* ff1_w = (const float*)d_in[23];
    const float* ff1_b = (const float*)d_in[24];
    const float* ff2_w = (const float*)d_in[25];
    const float* ff2_b = (const float*)d_in[26];
    const float* ln1_w = (const float*)d_in[27];
    const float* ln1_b = (const float*)d_in[28];
    const float* ln2_w = (const float*)d_in[29];
    const float* ln2_b = (const float*)d_in[30];
    const float* fln_w = (const float*)d_in[31];
    const float* fln_b = (const float*)d_in[32];
    const float* proj_w = (const float*)d_in[33];
    const float* proj_b = (const float*)d_in[34];

    mask_kernel<<<1, 256, 0, stream>>>(n_segs, (float*)d_out + 256 * NCLS);

    size_t off = 0;
    auto alloc = [&](size_t bytes) {
        void* p = (char*)d_ws + off;
        off += (bytes + 255) & ~(size_t)255;
        return p;
    };
    ushort* wbc = (ushort*)alloc(4194304ULL * 2);             // conv1-6 weights bf16, kw-major
    ushort* w0pad = (ushort*)alloc(512ULL * 32 * 2);          // conv0 weights padded
    ushort* c0buf = (ushort*)alloc((size_t)16001 * 512 * 2);  // conv0 chunk (aliases out2b/out5)
    ushort* out1 = (ushort*)alloc((size_t)15999 * 512 * 2);   // per-batch conv1 out
    ushort* out4 = (ushort*)alloc((size_t)4 * 1999 * 512 * 2);
    float* scores = (float*)alloc((size_t)4 * TP_ * 4);
    float* tokens = (float*)alloc((size_t)256 * DMODEL * 4);
    ushort* tokens_bf = (ushort*)alloc((size_t)256 * DMODEL * 2);
    float* qkv = (float*)alloc((size_t)256 * 2304 * 4);
    ushort* oall_bf = (ushort*)alloc((size_t)256 * DMODEL * 2);
    float* tmp = (float*)alloc((size_t)256 * DMODEL * 4);
    ushort* ffh_bf = (ushort*)alloc((size_t)256 * FFDIM * 2);
    float* ybuf = (float*)alloc((size_t)256 * DMODEL * 4);
    ushort* ybf = (ushort*)alloc((size_t)256 * DMODEL * 2);
    if (off > ws_size) return;  // diagnostic bail (mask already written)

    // aliases (lifetimes disjoint within each batch / phase)
    ushort* out2b = c0buf;                        // conv2 out (c0 dead after conv1)
    ushort* out3b = out1 + (size_t)12000 * 512;   // conv3 out (out1 dead after conv2)
    ushort* out5 = c0buf;                         // conv5 out (out2b dead after conv3)
    ushort* feats = out1;                         // conv6 out (out1 head free)

    ushort* wc1 = wbc, * wc2 = wbc + 786432, * wc3 = wbc + 1572864,
          * wc4 = wbc + 2359296, * wc5 = wbc + 2883584, * wc6 = wbc + 3407872;

    // ---- weight conversion ----
    convw_kernel<<<dim3(512, 7), 256, 0, stream>>>(cw[1], cw[2], cw[3], cw[4], cw[5], cw[6],
                                                   cw[0], wbc, w0pad);

    // ---- conv stack (bf16 MFMA); conv0+conv1 in two t-chunks, convs 5-6 z-batched ----
    for (int b = 0; b < BATCH; b++) {
        const float* xb = x + (size_t)b * TIN0;
        // chunk 0: t in [0,8000), u in [0,16001)
        conv0_mfma<<<dim3(126, 4), 256, 0, stream>>>(xb, w0pad, cb[0], c0buf, 0, 16001);
        conv_mfma<3, 2, 1, 1, 0><<<dim3(63, 4, 1), 256, 0, stream>>>(
            c0buf, wc1, nullptr, cb[1], out1, 512, 512, 8000, 0, 0, 0, 0);
        // chunk 1: t in [8000,15999), u in [16000,31999)
        conv0_mfma<<<dim3(125, 4), 256, 0, stream>>>(xb, w0pad, cb[0], c0buf, 16000, 15999);
        conv_mfma<3, 2, 1, 1, 0><<<dim3(63, 4, 1), 256, 0, stream>>>(
            c0buf, wc1, nullptr, cb[1], out1, 512, 512, 15999, 8000, 16000, 0, 0);
        conv_mfma<3, 2, 1, 1, 0><<<dim3(63, 4, 1), 256, 0, stream>>>(
            out1, wc2, nullptr, cb[2], out2b, 512, 512, 7999, 0, 0, 0, 0);
        conv_mfma<3, 2, 1, 1, 0><<<dim3(32, 4, 1), 256, 0, stream>>>(
            out2b, wc3, nullptr, cb[3], out3b, 512, 512, 3999, 0, 0, 0, 0);
        conv_mfma<2, 2, 1, 1, 0><<<dim3(16, 4, 1), 256, 0, stream>>>(
            out3b, wc4, nullptr, cb[4], out4 + (size_t)b * 1999 * 512,
            512, 512, 1999, 0, 0, 0, 0);
    }
    conv_mfma<2, 2, 1, 1, 0><<<dim3(8, 4, BATCH), 256, 0, stream>>>(
        out4, wc5, nullptr, cb[5], out5, 512, 512, 999, 0, 0,
        (long)1999 * 512, (long)999 * 512);
    conv_mfma<2, 2, 1, 1, 0><<<dim3(4, 6, BATCH), 256, 0, stream>>>(
        out5, wc6, nullptr, cb[6], feats, 512, 768, 499, 0, 0,
        (long)999 * 512, (long)499 * 768);

    // ---- pooling ----
    scores_kernel<<<dim3(125, 4), 256, 0, stream>>>(feats, attn_v, scores);
    pool_kernel<<<dim3(SMAX_, 4), 256, 0, stream>>>(feats, scores, seg_bounds, n_segs,
                                                    pos_emb, tokens, tokens_bf);

    // ---- transformer (bf16 MFMA GEMMs, fp32 weights staged+converted in-kernel) ----
    for (int l = 0; l < NLAYER; l++) {
        const float* iw = in_w + (size_t)l * 2304 * DMODEL;
        const float* ib = in_b + (size_t)l * 2304;
        const float* ow = out_w + (size_t)l * DMODEL * DMODEL;
        const float* ob = out_b + (size_t)l * DMODEL;
        const float* f1w = ff1_w + (size_t)l * FFDIM * DMODEL;
        const float* f1b = ff1_b + (size_t)l * FFDIM;
        const float* f2w = ff2_w + (size_t)l * DMODEL * FFDIM;
        const float* f2b_ = ff2_b + (size_t)l * DMODEL;

        conv_mfma<1, 1, 0, 0, 1><<<dim3(2, 18, 1), 256, 0, stream>>>(
            tokens_bf, nullptr, iw, ib, qkv, 768, 2304, 256, 0, 0, 0, 0);
        attn_kernel<<<dim3(12, 4), 256, 0, stream>>>(qkv, n_segs, oall_bf);
        conv_mfma<1, 1, 0, 0, 1><<<dim3(2, 6, 1), 256, 0, stream>>>(
            oall_bf, nullptr, ow, ob, tmp, 768, 768, 256, 0, 0, 0, 0);
        ln_kernel<<<256, 256, 0, stream>>>(tokens, tmp, ln1_w + l * DMODEL, ln1_b + l * DMODEL,
                                           tokens, tokens_bf);
        conv_mfma<1, 1, 1, 1, 1><<<dim3(2, 16, 1), 256, 0, stream>>>(
            tokens_bf, nullptr, f1w, f1b, ffh_bf, 768, FFDIM, 256, 0, 0, 0, 0);
        conv_mfma<1, 1, 0, 0, 1><<<dim3(2, 6, 1), 256, 0, stream>>>(
            ffh_bf, nullptr, f2w, f2b_, tmp, 2048, 768, 256, 0, 0, 0, 0);
        ln_kernel<<<256, 256, 0, stream>>>(tokens, tmp, ln2_w + l * DMODEL, ln2_b + l * DMODEL,
                                           tokens, tokens_bf);
    }

    // ---- head ----
    ln_kernel<<<256, 256, 0, stream>>>(tokens, nullptr, fln_w, fln_b, ybuf, ybf);
    conv_mfma<1, 1, 0, 0, 1><<<dim3(2, 1, 1), 256, 0, stream>>>(
        ybf, nullptr, proj_w, proj_b, (float*)d_out, 768, NCLS, 256, 0, 0, 0, 0);
}

// Round 5
// 2647.542 us; speedup vs baseline: 3.9271x; 1.5579x over previous
//
#include <hip/hip_runtime.h>
#include <hip/hip_bf16.h>

// ---------------- constants ----------------
#define BATCH 4
#define TIN0 160000
#define DMODEL 768
#define NLAYER 12
#define FFDIM 2048
#define NCLS 100
#define SMAX_ 64
#define TP_ 499

typedef __attribute__((ext_vector_type(8))) short short8;
typedef __attribute__((ext_vector_type(4))) float f32x4;

__device__ inline ushort f2b(float f) { __hip_bfloat16 h = __float2bfloat16(f); return *(ushort*)&h; }
__device__ inline float b2f(ushort u) { __hip_bfloat16 h = *(__hip_bfloat16*)&u; return __bfloat162float(h); }

__device__ inline void gl_lds16(const ushort* g, ushort* l) {
    __builtin_amdgcn_global_load_lds((const __attribute__((address_space(1))) unsigned int*)g,
                                     (__attribute__((address_space(3))) unsigned int*)l, 16, 0, 0);
}

// ---------------- reduction helpers ----------------
__device__ inline float wave_reduce_sum(float v) {
#pragma unroll
    for (int off = 32; off > 0; off >>= 1) v += __shfl_down(v, off, 64);
    return v;
}
__device__ inline float wave_reduce_max(float v) {
#pragma unroll
    for (int off = 32; off > 0; off >>= 1) v = fmaxf(v, __shfl_down(v, off, 64));
    return v;
}
__device__ inline float block_reduce_sum(float v, float* scratch) {
    v = wave_reduce_sum(v);
    int wid = threadIdx.x >> 6;
    if ((threadIdx.x & 63) == 0) scratch[wid] = v;
    __syncthreads();
    float r = scratch[0] + scratch[1] + scratch[2] + scratch[3];
    __syncthreads();
    return r;
}
__device__ inline float block_reduce_max(float v, float* scratch) {
    v = wave_reduce_max(v);
    int wid = threadIdx.x >> 6;
    if ((threadIdx.x & 63) == 0) scratch[wid] = v;
    __syncthreads();
    float r = fmaxf(fmaxf(scratch[0], scratch[1]), fmaxf(scratch[2], scratch[3]));
    __syncthreads();
    return r;
}

// =================================================================
// Generic MFMA implicit-GEMM conv / GEMM (conv stack + head).
// A time-major [.][Cin] bf16; weights [Cout][K], K kw-major.
// out[t][oc] = act( bias[oc] + sum_k W[oc][k] * A[STRIDE*t+kw - uBase][ic] )
// =================================================================
template <int KW, int STRIDE, int RELU, int OBF, int BF32>
__global__ __launch_bounds__(256) void conv_mfma(
    const ushort* __restrict__ A,
    const ushort* __restrict__ Wc,
    const float* __restrict__ Wf,
    const float* __restrict__ bias,
    void* __restrict__ outv,
    int Cin, int Cout, int Tout, int tBase, int uBase,
    long aStride, long oStride) {
    const int K = KW * Cin;
    const int nCh = K >> 5;
    const int CPK = Cin >> 5;
    const int t0 = tBase + blockIdx.x * 128;
    const int oc0 = blockIdx.y * 128;
    const int b = blockIdx.z;
    const ushort* Ab = A + (size_t)b * aStride;

    __shared__ ushort sA[4096];
    __shared__ ushort sB[4096];

    const int tid = threadIdx.x;
    const int lane = tid & 63;
    const int wv = tid >> 6;
    const int rsub = lane >> 2;
    const int kgW = (lane & 3) ^ ((lane >> 3) & 3);
    const int mrow = lane & 15;
    const int kq = lane >> 4;
    const int slot8 = (mrow * 4 + (kq ^ ((mrow >> 1) & 3))) * 8;

    f32x4 acc[2][8];
#pragma unroll
    for (int s = 0; s < 2; s++)
#pragma unroll
        for (int n = 0; n < 8; n++) acc[s][n] = (f32x4){0.f, 0.f, 0.f, 0.f};

    for (int c = 0; c < nCh; c++) {
        const int kw = (KW == 1) ? 0 : (c / CPK);
        const int icc = (c - kw * CPK) << 5;
#pragma unroll
        for (int j = 0; j < 2; j++) {
            int t = t0 + j * 64 + wv * 16 + rsub;
            if (t > Tout - 1) t = Tout - 1;
            int u = STRIDE * t + kw - uBase;
            gl_lds16(Ab + (size_t)u * Cin + icc + kgW * 8, &sA[(j * 64 + wv * 16) * 32]);
        }
#pragma unroll
        for (int j = 0; j < 2; j++) {
            int rowb = oc0 + j * 64 + wv * 16 + rsub;
            if (rowb > Cout - 1) rowb = Cout - 1;
            if (BF32) {
                const float* wp = Wf + (size_t)rowb * K + c * 32 + kgW * 8;
                float4 w0_ = *(const float4*)wp;
                float4 w1_ = *(const float4*)(wp + 4);
                short8 vals;
                vals[0] = (short)f2b(w0_.x); vals[1] = (short)f2b(w0_.y);
                vals[2] = (short)f2b(w0_.z); vals[3] = (short)f2b(w0_.w);
                vals[4] = (short)f2b(w1_.x); vals[5] = (short)f2b(w1_.y);
                vals[6] = (short)f2b(w1_.z); vals[7] = (short)f2b(w1_.w);
                *(short8*)&sB[(j * 64 + wv * 16) * 32 + lane * 8] = vals;
            } else {
                gl_lds16(Wc + (size_t)rowb * K + c * 32 + kgW * 8, &sB[(j * 64 + wv * 16) * 32]);
            }
        }
        __syncthreads();
        short8 a0 = *(const short8*)&sA[(wv * 32 + 0) * 32 + slot8];
        short8 a1 = *(const short8*)&sA[(wv * 32 + 16) * 32 + slot8];
#pragma unroll
        for (int n = 0; n < 8; n++) {
            short8 bf = *(const short8*)&sB[(n * 16) * 32 + slot8];
            acc[0][n] = __builtin_amdgcn_mfma_f32_16x16x32_bf16(a0, bf, acc[0][n], 0, 0, 0);
            acc[1][n] = __builtin_amdgcn_mfma_f32_16x16x32_bf16(a1, bf, acc[1][n], 0, 0, 0);
        }
        __syncthreads();
    }

    float* outf = (float*)outv + (size_t)b * oStride;
    ushort* outh = (ushort*)outv + (size_t)b * oStride;
    float bz[8];
#pragma unroll
    for (int n = 0; n < 8; n++) {
        int oc = oc0 + n * 16 + mrow;
        bz[n] = (oc < Cout) ? bias[oc] : 0.f;
    }
#pragma unroll
    for (int s = 0; s < 2; s++) {
        int tb = t0 + wv * 32 + s * 16 + kq * 4;
#pragma unroll
        for (int n = 0; n < 8; n++) {
            int oc = oc0 + n * 16 + mrow;
            if (oc >= Cout) continue;
#pragma unroll
            for (int r = 0; r < 4; r++) {
                int t = tb + r;
                if (t < Tout) {
                    float v = acc[s][n][r] + bz[n];
                    if (RELU) v = fmaxf(v, 0.f);
                    if (OBF) outh[(size_t)t * Cout + oc] = f2b(v);
                    else outf[(size_t)t * Cout + oc] = v;
                }
            }
        }
    }
}

// =================================================================
// Split-K GEMM for transformer: A bf16 [256][K], W fp32 [M][K].
// Block (tx, ty, kc) computes 128x128 tile over K-chunk kc (KCH cols),
// plain-stores fp32 partial into slab kc: outp[kc*oSlab + t*M + oc].
// kc==0 slab includes bias. Consumers sum the slabs.
// M multiple of 128; tokens = 256.
// =================================================================
__global__ __launch_bounds__(256) void gemm_sk(
    const ushort* __restrict__ A, const float* __restrict__ Wf,
    const float* __restrict__ bias, float* __restrict__ outp,
    int M, int K, int KCH, long oSlab) {
    __shared__ ushort sA[4096];
    __shared__ ushort sB[4096];
    const int tid = threadIdx.x;
    const int lane = tid & 63;
    const int wv = tid >> 6;
    const int rsub = lane >> 2;
    const int kgW = (lane & 3) ^ ((lane >> 3) & 3);
    const int mrow = lane & 15;
    const int kq = lane >> 4;
    const int slot8 = (mrow * 4 + (kq ^ ((mrow >> 1) & 3))) * 8;
    const int t0 = blockIdx.x * 128;
    const int oc0 = blockIdx.y * 128;
    const int kc = blockIdx.z;
    const int k0 = kc * KCH;

    f32x4 acc[2][8];
#pragma unroll
    for (int s = 0; s < 2; s++)
#pragma unroll
        for (int n = 0; n < 8; n++) acc[s][n] = (f32x4){0.f, 0.f, 0.f, 0.f};

    const int nIt = KCH >> 5;
    for (int c = 0; c < nIt; c++) {
        const int kk = k0 + (c << 5);
#pragma unroll
        for (int j = 0; j < 2; j++) {
            int t = t0 + j * 64 + wv * 16 + rsub;
            gl_lds16(A + (size_t)t * K + kk + kgW * 8, &sA[(j * 64 + wv * 16) * 32]);
        }
#pragma unroll
        for (int j = 0; j < 2; j++) {
            int rowb = oc0 + j * 64 + wv * 16 + rsub;
            const float* wp = Wf + (size_t)rowb * K + kk + kgW * 8;
            float4 w0_ = *(const float4*)wp;
            float4 w1_ = *(const float4*)(wp + 4);
            short8 vals;
            vals[0] = (short)f2b(w0_.x); vals[1] = (short)f2b(w0_.y);
            vals[2] = (short)f2b(w0_.z); vals[3] = (short)f2b(w0_.w);
            vals[4] = (short)f2b(w1_.x); vals[5] = (short)f2b(w1_.y);
            vals[6] = (short)f2b(w1_.z); vals[7] = (short)f2b(w1_.w);
            *(short8*)&sB[(j * 64 + wv * 16) * 32 + lane * 8] = vals;
        }
        __syncthreads();
        short8 a0 = *(const short8*)&sA[(wv * 32 + 0) * 32 + slot8];
        short8 a1 = *(const short8*)&sA[(wv * 32 + 16) * 32 + slot8];
#pragma unroll
        for (int n = 0; n < 8; n++) {
            short8 bf = *(const short8*)&sB[(n * 16) * 32 + slot8];
            acc[0][n] = __builtin_amdgcn_mfma_f32_16x16x32_bf16(a0, bf, acc[0][n], 0, 0, 0);
            acc[1][n] = __builtin_amdgcn_mfma_f32_16x16x32_bf16(a1, bf, acc[1][n], 0, 0, 0);
        }
        __syncthreads();
    }

    float* op = outp + (size_t)kc * oSlab;
#pragma unroll
    for (int s = 0; s < 2; s++) {
        int tb = t0 + wv * 32 + s * 16 + kq * 4;
#pragma unroll
        for (int n = 0; n < 8; n++) {
            int oc = oc0 + n * 16 + mrow;
            float bz = (kc == 0) ? bias[oc] : 0.f;
#pragma unroll
            for (int r = 0; r < 4; r++) {
                op[(size_t)(tb + r) * M + oc] = acc[s][n][r] + bz;
            }
        }
    }
}

// ---------------- relu(sum of 3 slabs) -> bf16 ----------------
__global__ __launch_bounds__(256) void relu_cast(const float* __restrict__ p,
                                                 ushort* __restrict__ o,
                                                 long n, long slab) {
    for (long i = (long)blockIdx.x * 1024 + threadIdx.x; i < n; i += (long)gridDim.x * 1024) {
#pragma unroll
        for (int j = 0; j < 4; j++) {
            long k = i + (long)j * 256;
            if (k < n) {
                float v = p[k] + p[k + slab] + p[k + 2 * slab];
                o[k] = f2b(fmaxf(v, 0.f));
            }
        }
    }
}

// =================================================================
// conv0 as MFMA GEMM
// =================================================================
__global__ __launch_bounds__(256) void conv0_mfma(const float* __restrict__ x,
                                                  const ushort* __restrict__ w0pad,
                                                  const float* __restrict__ b0,
                                                  ushort* __restrict__ c0,
                                                  int uBase, int nU) {
    __shared__ ushort sA[4096];
    __shared__ ushort sB[4096];
    const int tid = threadIdx.x;
    const int lane = tid & 63;
    const int wv = tid >> 6;
    const int rsub = lane >> 2;
    const int kgW = (lane & 3) ^ ((lane >> 3) & 3);
    const int mrow = lane & 15;
    const int kq = lane >> 4;
    const int slot8 = (mrow * 4 + (kq ^ ((mrow >> 1) & 3))) * 8;
    const int r0 = blockIdx.x * 128;
    const int oc0 = blockIdx.y * 128;

    f32x4 acc[2][8];
#pragma unroll
    for (int s = 0; s < 2; s++)
#pragma unroll
        for (int n = 0; n < 8; n++) acc[s][n] = (f32x4){0.f, 0.f, 0.f, 0.f};

#pragma unroll
    for (int j = 0; j < 2; j++) {
        int r = r0 + j * 64 + wv * 16 + rsub;
        if (r > nU - 1) r = nU - 1;
        const float* xp = x + (size_t)5 * (uBase + r);
        short8 vals = (short8){0, 0, 0, 0, 0, 0, 0, 0};
        if (kgW == 0) {
#pragma unroll
            for (int q = 0; q < 8; q++) vals[q] = (short)f2b(xp[q]);
        } else if (kgW == 1) {
            vals[0] = (short)f2b(xp[8]);
            vals[1] = (short)f2b(xp[9]);
        }
        *(short8*)&sA[(j * 64 + wv * 16) * 32 + lane * 8] = vals;
    }
#pragma unroll
    for (int j = 0; j < 2; j++) {
        int rowb = oc0 + j * 64 + wv * 16 + rsub;
        gl_lds16(w0pad + (size_t)rowb * 32 + kgW * 8, &sB[(j * 64 + wv * 16) * 32]);
    }
    __syncthreads();
    short8 a0 = *(const short8*)&sA[(wv * 32 + 0) * 32 + slot8];
    short8 a1 = *(const short8*)&sA[(wv * 32 + 16) * 32 + slot8];
#pragma unroll
    for (int n = 0; n < 8; n++) {
        short8 bf = *(const short8*)&sB[(n * 16) * 32 + slot8];
        acc[0][n] = __builtin_amdgcn_mfma_f32_16x16x32_bf16(a0, bf, acc[0][n], 0, 0, 0);
        acc[1][n] = __builtin_amdgcn_mfma_f32_16x16x32_bf16(a1, bf, acc[1][n], 0, 0, 0);
    }
#pragma unroll
    for (int s = 0; s < 2; s++) {
        int rb = r0 + wv * 32 + s * 16 + kq * 4;
#pragma unroll
        for (int n = 0; n < 8; n++) {
            int oc = oc0 + n * 16 + mrow;
            float bz = b0[oc];
#pragma unroll
            for (int r = 0; r < 4; r++) {
                int rr = rb + r;
                if (rr < nU) c0[(size_t)rr * 512 + oc] = f2b(fmaxf(acc[s][n][r] + bz, 0.f));
            }
        }
    }
}

// ---------------- conv-weight permute+cast ----------------
__global__ __launch_bounds__(256) void convw_kernel(
    const float* __restrict__ w1, const float* __restrict__ w2, const float* __restrict__ w3,
    const float* __restrict__ w4, const float* __restrict__ w5, const float* __restrict__ w6,
    const float* __restrict__ w0, ushort* __restrict__ dst, ushort* __restrict__ dw0) {
    const int z = blockIdx.y;
    const int COUTS[6] = {512, 512, 512, 512, 512, 768};
    const int KWS[6] = {3, 3, 3, 2, 2, 2};
    const long OFFS[6] = {0, 786432, 1572864, 2359296, 2883584, 3407872};
    const float* srcs[6] = {w1, w2, w3, w4, w5, w6};
    if (z == 6) {
        for (int o = blockIdx.x * 256 + threadIdx.x; o < 512 * 32; o += gridDim.x * 256) {
            int oc = o >> 5, q = o & 31;
            dw0[o] = (q < 10) ? f2b(w0[oc * 10 + q]) : (ushort)0;
        }
        return;
    }
    const float* src = srcs[z];
    ushort* d = dst + OFFS[z];
    const int Cin = 512, Kw = KWS[z];
    const int K = Cin * Kw;
    const long n = (long)COUTS[z] * K;
    for (long o = blockIdx.x * 256 + threadIdx.x; o < n; o += (long)gridDim.x * 256) {
        long oc = o / K;
        int rem = (int)(o - oc * K);
        int kw = rem / Cin, ic = rem - kw * Cin;
        d[o] = f2b(src[(oc * Cin + ic) * Kw + kw]);
    }
}

// ---------------- scores ----------------
__global__ __launch_bounds__(256) void scores_kernel(const ushort* __restrict__ feats,
                                                     const float* __restrict__ v,
                                                     float* __restrict__ scores) {
    int b = blockIdx.y;
    int t = blockIdx.x * 4 + (threadIdx.x >> 6);
    if (t >= TP_) return;
    int lane = threadIdx.x & 63;
    const ushort* f = feats + ((size_t)b * TP_ + t) * DMODEL + lane * 12;
    float acc = 0.f;
#pragma unroll
    for (int q = 0; q < 12; q++) acc = fmaf(b2f(f[q]), v[lane * 12 + q], acc);
    acc = wave_reduce_sum(acc);
    if (lane == 0) scores[b * TP_ + t] = acc;
}

// ---------------- per-segment softmax pooling + pos_emb ----------------
__global__ __launch_bounds__(256) void pool_kernel(const ushort* __restrict__ featsAll,
                                                   const float* __restrict__ scoresAll,
                                                   const int* __restrict__ seg_bounds,
                                                   const int* __restrict__ n_segs,
                                                   const float* __restrict__ pos_emb,
                                                   float* __restrict__ tokens,
                                                   ushort* __restrict__ tokens_bf) {
    __shared__ float scratch[4];
    __shared__ float wgt[512];
    int s = blockIdx.x, b = blockIdx.y, tid = threadIdx.x;
    float* tout = tokens + ((size_t)b * SMAX_ + s) * DMODEL;
    ushort* tbf = tokens_bf + ((size_t)b * SMAX_ + s) * DMODEL;
    int ns = n_segs[b];
    if (s >= ns) {
        for (int c = tid; c < DMODEL; c += 256) {
            float v = pos_emb[s * DMODEL + c];
            tout[c] = v; tbf[c] = f2b(v);
        }
        return;
    }
    const float* sc = scoresAll + b * TP_;
    int b0 = seg_bounds[b * (SMAX_ + 1) + s];
    int b1 = seg_bounds[b * (SMAX_ + 1) + s + 1];
    int st = min(max(b0, 0), TP_ - 1);
    int en = max(st + 1, min(max(b1, 0), TP_));
    float lm = -1e30f;
    for (int t = st + tid; t < en; t += 256) lm = fmaxf(lm, sc[t]);
    float m = block_reduce_max(lm, scratch);
    float ls = 0.f;
    for (int t = st + tid; t < en; t += 256) ls += __expf(sc[t] - m);
    float den = block_reduce_sum(ls, scratch);
    float inv = 1.f / den;
    for (int t = st + tid; t < en; t += 256) wgt[t - st] = __expf(sc[t] - m) * inv;
    __syncthreads();
    int len = en - st;
    const ushort* f = featsAll + ((size_t)b * TP_ + st) * DMODEL;
    float a0 = 0.f, a1 = 0.f, a2 = 0.f;
    for (int t = 0; t < len; t++) {
        float wv = wgt[t];
        const ushort* fr = f + (size_t)t * DMODEL;
        a0 = fmaf(wv, b2f(fr[tid]), a0);
        a1 = fmaf(wv, b2f(fr[tid + 256]), a1);
        a2 = fmaf(wv, b2f(fr[tid + 512]), a2);
    }
    float v0 = a0 + pos_emb[s * DMODEL + tid];
    float v1 = a1 + pos_emb[s * DMODEL + tid + 256];
    float v2 = a2 + pos_emb[s * DMODEL + tid + 512];
    tout[tid] = v0; tout[tid + 256] = v1; tout[tid + 512] = v2;
    tbf[tid] = f2b(v0); tbf[tid + 256] = f2b(v1); tbf[tid + 512] = f2b(v2);
}

// ---------------- attention: qkv from 3 fp32 partial slabs ----------------
__global__ __launch_bounds__(256) void attn_kernel(const float* __restrict__ qkv_p,
                                                   const int* __restrict__ n_segs,
                                                   ushort* __restrict__ o, long slab) {
    __shared__ float sK[64][68];
    __shared__ float sV[64][68];
    __shared__ float sS[64][68];
    int h = blockIdx.x, b = blockIdx.y, tid = threadIdx.x;
    int ns = n_segs[b];
    const float* base = qkv_p + (size_t)b * 64 * 2304 + h * 64;
    for (int idx = tid; idx < 4096; idx += 256) {
        int s_ = idx >> 6, d = idx & 63;
        size_t kofs = (size_t)s_ * 2304 + 768 + d;
        size_t vofs = (size_t)s_ * 2304 + 1536 + d;
        sK[s_][d] = base[kofs] + base[kofs + slab] + base[kofs + 2 * slab];
        sV[s_][d] = base[vofs] + base[vofs + slab] + base[vofs + 2 * slab];
    }
    __syncthreads();
    int qr = tid >> 2;
    int c0 = (tid & 3) * 16;
    const float* qrow = base + (size_t)qr * 2304;
    float acc[16];
#pragma unroll
    for (int j = 0; j < 16; j++) acc[j] = 0.f;
    for (int d = 0; d < 64; d += 4) {
        float4 q0 = *(const float4*)(qrow + d);
        float4 q1 = *(const float4*)(qrow + slab + d);
        float4 q2 = *(const float4*)(qrow + 2 * slab + d);
        float4 qv = make_float4(q0.x + q1.x + q2.x, q0.y + q1.y + q2.y,
                                q0.z + q1.z + q2.z, q0.w + q1.w + q2.w);
#pragma unroll
        for (int j = 0; j < 16; j++) {
            float4 kv = *(const float4*)&sK[c0 + j][d];
            acc[j] += qv.x * kv.x + qv.y * kv.y + qv.z * kv.z + qv.w * kv.w;
        }
    }
#pragma unroll
    for (int j = 0; j < 16; j++) {
        int kc = c0 + j;
        float vv = acc[j] * 0.125f;
        if (kc >= ns) vv = -1e9f;
        sS[qr][kc] = vv;
    }
    __syncthreads();
    if (tid < 64) {
        float m = -1e30f;
#pragma unroll 4
        for (int k = 0; k < 64; k++) m = fmaxf(m, sS[tid][k]);
        float ssum = 0.f;
#pragma unroll 4
        for (int k = 0; k < 64; k++) {
            float e = __expf(sS[tid][k] - m);
            sS[tid][k] = e;
            ssum += e;
        }
        float inv = 1.f / ssum;
#pragma unroll 4
        for (int k = 0; k < 64; k++) sS[tid][k] *= inv;
    }
    __syncthreads();
    float4 oacc[4];
#pragma unroll
    for (int j = 0; j < 4; j++) oacc[j] = make_float4(0.f, 0.f, 0.f, 0.f);
    for (int k = 0; k < 64; k++) {
        float wv = sS[qr][k];
#pragma unroll
        for (int j4 = 0; j4 < 4; j4++) {
            float4 vv = *(const float4*)&sV[k][c0 + j4 * 4];
            oacc[j4].x = fmaf(wv, vv.x, oacc[j4].x);
            oacc[j4].y = fmaf(wv, vv.y, oacc[j4].y);
            oacc[j4].z = fmaf(wv, vv.z, oacc[j4].z);
            oacc[j4].w = fmaf(wv, vv.w, oacc[j4].w);
        }
    }
    ushort* orow = o + ((size_t)b * 64 + qr) * DMODEL + h * 64 + c0;
#pragma unroll
    for (int j4 = 0; j4 < 4; j4++) {
        orow[j4 * 4 + 0] = f2b(oacc[j4].x);
        orow[j4 * 4 + 1] = f2b(oacc[j4].y);
        orow[j4 * 4 + 2] = f2b(oacc[j4].z);
        orow[j4 * 4 + 3] = f2b(oacc[j4].w);
    }
}

// ---------------- layernorm; residual = sum of nP fp32 slabs ----------------
__global__ __launch_bounds__(256) void ln_kernel(const float* __restrict__ x,
                                                 const float* __restrict__ rP, int nP, long rSlab,
                                                 const float* __restrict__ w,
                                                 const float* __restrict__ b,
                                                 float* __restrict__ out,
                                                 ushort* __restrict__ outbf) {
    __shared__ float scratch[4];
    int row = blockIdx.x, tid = threadIdx.x;
    const float* xr = x + (size_t)row * DMODEL;
    float v0 = xr[tid], v1 = xr[tid + 256], v2 = xr[tid + 512];
    for (int p = 0; p < nP; p++) {
        const float* rr = rP + (size_t)p * rSlab + (size_t)row * DMODEL;
        v0 += rr[tid]; v1 += rr[tid + 256]; v2 += rr[tid + 512];
    }
    float mean = block_reduce_sum(v0 + v1 + v2, scratch) * (1.f / DMODEL);
    float d0 = v0 - mean, d1 = v1 - mean, d2 = v2 - mean;
    float var = block_reduce_sum(d0 * d0 + d1 * d1 + d2 * d2, scratch) * (1.f / DMODEL);
    float inv = rsqrtf(var + 1e-5f);
    float o0 = d0 * inv * w[tid] + b[tid];
    float o1 = d1 * inv * w[tid + 256] + b[tid + 256];
    float o2 = d2 * inv * w[tid + 512] + b[tid + 512];
    float* orow = out + (size_t)row * DMODEL;
    orow[tid] = o0; orow[tid + 256] = o1; orow[tid + 512] = o2;
    if (outbf) {
        ushort* obf = outbf + (size_t)row * DMODEL;
        obf[tid] = f2b(o0); obf[tid + 256] = f2b(o1); obf[tid + 512] = f2b(o2);
    }
}

// ---------------- pad mask output ----------------
__global__ void mask_kernel(const int* __restrict__ n_segs, float* __restrict__ mout) {
    int i = threadIdx.x;
    int b = i >> 6, s = i & 63;
    mout[i] = (s >= n_segs[b]) ? 1.0f : 0.0f;
}

// ---------------- host ----------------
extern "C" void kernel_launch(void* const* d_in, const int* in_sizes, int n_in,
                              void* d_out, int out_size, void* d_ws, size_t ws_size,
                              hipStream_t stream) {
    const float* x = (const float*)d_in[0];
    const int* seg_bounds = (const int*)d_in[1];
    const int* n_segs = (const int*)d_in[2];
    const float* cw[7], * cb[7];
    for (int i = 0; i < 7; i++) { cw[i] = (const float*)d_in[3 + 2 * i]; cb[i] = (const float*)d_in[4 + 2 * i]; }
    const float* attn_v = (const float*)d_in[17];
    const float* pos_emb = (const float*)d_in[18];
    const float* in_w = (const float*)d_in[19];
    const float* in_b = (const float*)d_in[20];
    const float* out_w = (const float*)d_in[21];
    const float* out_b = (const float*)d_in[22];
    const float* ff1_w = (const float*)d_in[23];
    const float* ff1_b = (const float*)d_in[24];
    const float* ff2_w = (const float*)d_in[25];
    const float* ff2_b = (const float*)d_in[26];
    const float* ln1_w = (const float*)d_in[27];
    const float* ln1_b = (const float*)d_in[28];
    const float* ln2_w = (const float*)d_in[29];
    const float* ln2_b = (const float*)d_in[30];
    const float* fln_w = (const float*)d_in[31];
    const float* fln_b = (const float*)d_in[32];
    const float* proj_w = (const float*)d_in[33];
    const float* proj_b = (const float*)d_in[34];

    mask_kernel<<<1, 256, 0, stream>>>(n_segs, (float*)d_out + 256 * NCLS);

    size_t off = 0;
    auto alloc = [&](size_t bytes) {
        void* p = (char*)d_ws + off;
        off += (bytes + 255) & ~(size_t)255;
        return p;
    };
    ushort* wbc = (ushort*)alloc(4194304ULL * 2);
    ushort* w0pad = (ushort*)alloc(512ULL * 32 * 2);
    ushort* c0buf = (ushort*)alloc((size_t)16001 * 512 * 2);  // 16.39 MB, reused by transformer
    ushort* out1 = (ushort*)alloc((size_t)15999 * 512 * 2);
    ushort* out4 = (ushort*)alloc((size_t)4 * 1999 * 512 * 2); // 8.18 MB, reused by transformer
    float* scores = (float*)alloc((size_t)4 * TP_ * 4);
    float* tokens = (float*)alloc((size_t)256 * DMODEL * 4);
    ushort* tokens_bf = (ushort*)alloc((size_t)256 * DMODEL * 2);
    ushort* oall_bf = (ushort*)alloc((size_t)256 * DMODEL * 2);
    float* ybuf = (float*)alloc((size_t)256 * DMODEL * 4);
    ushort* ybf = (ushort*)alloc((size_t)256 * DMODEL * 2);
    if (off > ws_size) return;  // diagnostic bail

    // conv-phase aliases
    ushort* out2b = c0buf;
    ushort* out3b = out1 + (size_t)12000 * 512;
    ushort* out5 = c0buf;
    ushort* feats = out1;
    // transformer-phase aliases (c0buf/out4 dead after conv stack; feats=out1 survives)
    float* qkv_p = (float*)c0buf;                          // 3 x [256][2304] fp32 = 7.08 MB
    float* ffh_p = (float*)c0buf + (size_t)3 * 256 * 2304; // 3 x [256][2048] fp32 = 6.29 MB
    ushort* ffh_bf = (ushort*)(ffh_p + (size_t)3 * 256 * 2048); // [256][2048] bf16 = 1.05 MB
    float* tmp_p = (float*)out4;                           // 4 x [256][768] fp32 = 3.15 MB

    ushort* wc1 = wbc, * wc2 = wbc + 786432, * wc3 = wbc + 1572864,
          * wc4 = wbc + 2359296, * wc5 = wbc + 2883584, * wc6 = wbc + 3407872;

    convw_kernel<<<dim3(512, 7), 256, 0, stream>>>(cw[1], cw[2], cw[3], cw[4], cw[5], cw[6],
                                                   cw[0], wbc, w0pad);

    // ---- conv stack ----
    for (int b = 0; b < BATCH; b++) {
        const float* xb = x + (size_t)b * TIN0;
        conv0_mfma<<<dim3(126, 4), 256, 0, stream>>>(xb, w0pad, cb[0], c0buf, 0, 16001);
        conv_mfma<3, 2, 1, 1, 0><<<dim3(63, 4, 1), 256, 0, stream>>>(
            c0buf, wc1, nullptr, cb[1], out1, 512, 512, 8000, 0, 0, 0, 0);
        conv0_mfma<<<dim3(125, 4), 256, 0, stream>>>(xb, w0pad, cb[0], c0buf, 16000, 15999);
        conv_mfma<3, 2, 1, 1, 0><<<dim3(63, 4, 1), 256, 0, stream>>>(
            c0buf, wc1, nullptr, cb[1], out1, 512, 512, 15999, 8000, 16000, 0, 0);
        conv_mfma<3, 2, 1, 1, 0><<<dim3(63, 4, 1), 256, 0, stream>>>(
            out1, wc2, nullptr, cb[2], out2b, 512, 512, 7999, 0, 0, 0, 0);
        conv_mfma<3, 2, 1, 1, 0><<<dim3(32, 4, 1), 256, 0, stream>>>(
            out2b, wc3, nullptr, cb[3], out3b, 512, 512, 3999, 0, 0, 0, 0);
        conv_mfma<2, 2, 1, 1, 0><<<dim3(16, 4, 1), 256, 0, stream>>>(
            out3b, wc4, nullptr, cb[4], out4 + (size_t)b * 1999 * 512,
            512, 512, 1999, 0, 0, 0, 0);
    }
    conv_mfma<2, 2, 1, 1, 0><<<dim3(8, 4, BATCH), 256, 0, stream>>>(
        out4, wc5, nullptr, cb[5], out5, 512, 512, 999, 0, 0,
        (long)1999 * 512, (long)999 * 512);
    conv_mfma<2, 2, 1, 1, 0><<<dim3(4, 6, BATCH), 256, 0, stream>>>(
        out5, wc6, nullptr, cb[6], feats, 512, 768, 499, 0, 0,
        (long)999 * 512, (long)499 * 768);

    // ---- pooling ----
    scores_kernel<<<dim3(125, 4), 256, 0, stream>>>(feats, attn_v, scores);
    pool_kernel<<<dim3(SMAX_, 4), 256, 0, stream>>>(feats, scores, seg_bounds, n_segs,
                                                    pos_emb, tokens, tokens_bf);

    // ---- transformer (split-K GEMMs, fp32 weights read directly) ----
    const long qkvSlab = (long)256 * 2304;
    const long tmpSlab = (long)256 * 768;
    const long ffhSlab = (long)256 * 2048;
    for (int l = 0; l < NLAYER; l++) {
        const float* iw = in_w + (size_t)l * 2304 * DMODEL;
        const float* ib = in_b + (size_t)l * 2304;
        const float* ow = out_w + (size_t)l * DMODEL * DMODEL;
        const float* ob = out_b + (size_t)l * DMODEL;
        const float* f1w = ff1_w + (size_t)l * FFDIM * DMODEL;
        const float* f1b = ff1_b + (size_t)l * FFDIM;
        const float* f2w = ff2_w + (size_t)l * DMODEL * FFDIM;
        const float* f2b_ = ff2_b + (size_t)l * DMODEL;

        gemm_sk<<<dim3(2, 18, 3), 256, 0, stream>>>(tokens_bf, iw, ib, qkv_p, 2304, 768, 256, qkvSlab);
        attn_kernel<<<dim3(12, 4), 256, 0, stream>>>(qkv_p, n_segs, oall_bf, qkvSlab);
        gemm_sk<<<dim3(2, 6, 3), 256, 0, stream>>>(oall_bf, ow, ob, tmp_p, 768, 768, 256, tmpSlab);
        ln_kernel<<<256, 256, 0, stream>>>(tokens, tmp_p, 3, tmpSlab,
                                           ln1_w + l * DMODEL, ln1_b + l * DMODEL, tokens, tokens_bf);
        gemm_sk<<<dim3(2, 16, 3), 256, 0, stream>>>(tokens_bf, f1w, f1b, ffh_p, 2048, 768, 256, ffhSlab);
        relu_cast<<<512, 256, 0, stream>>>(ffh_p, ffh_bf, (long)256 * 2048, ffhSlab);
        gemm_sk<<<dim3(2, 6, 4), 256, 0, stream>>>(ffh_bf, f2w, f2b_, tmp_p, 768, 2048, 512, tmpSlab);
        ln_kernel<<<256, 256, 0, stream>>>(tokens, tmp_p, 4, tmpSlab,
                                           ln2_w + l * DMODEL, ln2_b + l * DMODEL, tokens, tokens_bf);
    }

    // ---- head ----
    ln_kernel<<<256, 256, 0, stream>>>(tokens, nullptr, 0, 0, fln_w, fln_b, ybuf, ybf);
    conv_mfma<1, 1, 0, 0, 1><<<dim3(2, 1, 1), 256, 0, stream>>>(
        ybf, nullptr, proj_w, proj_b, (float*)d_out, 768, NCLS, 256, 0, 0, 0, 0);
}

// Round 6
// 2554.835 us; speedup vs baseline: 4.0696x; 1.0363x over previous
//
#include <hip/hip_runtime.h>
#include <hip/hip_bf16.h>

// ---------------- constants ----------------
#define BATCH 4
#define TIN0 160000
#define DMODEL 768
#define NLAYER 12
#define FFDIM 2048
#define NCLS 100
#define SMAX_ 64
#define TP_ 499

typedef __attribute__((ext_vector_type(8))) short short8;
typedef __attribute__((ext_vector_type(4))) float f32x4;

__device__ inline ushort f2b(float f) { __hip_bfloat16 h = __float2bfloat16(f); return *(ushort*)&h; }
__device__ inline float b2f(ushort u) { __hip_bfloat16 h = *(__hip_bfloat16*)&u; return __bfloat162float(h); }

__device__ inline void gl_lds16(const ushort* g, ushort* l) {
    __builtin_amdgcn_global_load_lds((const __attribute__((address_space(1))) unsigned int*)g,
                                     (__attribute__((address_space(3))) unsigned int*)l, 16, 0, 0);
}

// ---------------- reduction helpers ----------------
__device__ inline float wave_reduce_sum(float v) {
#pragma unroll
    for (int off = 32; off > 0; off >>= 1) v += __shfl_down(v, off, 64);
    return v;
}
__device__ inline float wave_reduce_max(float v) {
#pragma unroll
    for (int off = 32; off > 0; off >>= 1) v = fmaxf(v, __shfl_down(v, off, 64));
    return v;
}
__device__ inline float block_reduce_sum(float v, float* scratch) {
    v = wave_reduce_sum(v);
    int wid = threadIdx.x >> 6;
    if ((threadIdx.x & 63) == 0) scratch[wid] = v;
    __syncthreads();
    float r = scratch[0] + scratch[1] + scratch[2] + scratch[3];
    __syncthreads();
    return r;
}
__device__ inline float block_reduce_max(float v, float* scratch) {
    v = wave_reduce_max(v);
    int wid = threadIdx.x >> 6;
    if ((threadIdx.x & 63) == 0) scratch[wid] = v;
    __syncthreads();
    float r = fmaxf(fmaxf(scratch[0], scratch[1]), fmaxf(scratch[2], scratch[3]));
    __syncthreads();
    return r;
}

// =================================================================
// Conv MFMA, kw-inner: A staged ONCE per 64-ic chunk (even/odd row
// buffers), reused across all KW taps. t-tile 128, oc-tile 128, 4 waves.
// A rows [.][Cin] bf16, Wc [Cout][KW*Cin] kw-major bf16, out [T][Cout] bf16.
// out[t][oc] = relu(bias[oc] + sum W[oc][kw*Cin+ic] * A[2t+kw-uBase][ic])
// LDS A: rows at 128B stride, 16B groups XOR-swizzled by (row&7) -> 2-way
// bank aliasing only (free). B: 64B rows, group swizzle by (row>>1)&3.
// =================================================================
template <int KW>
__global__ __launch_bounds__(256) void convT_mfma(
    const ushort* __restrict__ A,
    const ushort* __restrict__ Wc,
    const float* __restrict__ bias,
    ushort* __restrict__ outp,
    int Cin, int Cout, int Tout,
    int tBase, int uBase, int uMax,
    long aStride, long oStride) {
    constexpr int EB = 132;            // even-row region (rows)
    __shared__ ushort sA[288 * 64];    // 36.9 KB
    __shared__ ushort sB[KW * 128 * 32];
    const int tid = threadIdx.x;
    const int lane = tid & 63;
    const int wv = tid >> 6;
    const int mrow = lane & 15;
    const int kq = lane >> 4;
    const int t0 = tBase + blockIdx.x * 128;
    const int oc0 = blockIdx.y * 128;
    const ushort* Ab = A + (size_t)blockIdx.z * aStride;
    ushort* outb = outp + (size_t)blockIdx.z * oStride;
    const int K = KW * Cin;

    f32x4 acc[2][8];
#pragma unroll
    for (int s = 0; s < 2; s++)
#pragma unroll
        for (int n = 0; n < 8; n++) acc[s][n] = (f32x4){0.f, 0.f, 0.f, 0.f};

    const int nC8 = Cin >> 6;
    for (int c8 = 0; c8 < nC8; c8++) {
        const int ic0 = c8 << 6;
        // ---- stage A (even rows 0..131, odd rows 132..259; 288 padded) ----
#pragma unroll
        for (int rd = 0; rd < 9; rd++) {
            int slotBase = rd * 256 + wv * 64;
            int slot = slotBase + lane;
            int r = slot >> 3;
            int g = (slot & 7) ^ (r & 7);
            int u = (r < EB) ? (2 * t0 + 2 * r) : (2 * t0 + 2 * (r - EB) + 1);
            u -= uBase;
            if (u < 0) u = 0;
            if (u > uMax) u = uMax;
            gl_lds16(Ab + (size_t)u * Cin + ic0 + g * 8, &sA[slotBase * 8]);
        }
#pragma unroll
        for (int h = 0; h < 2; h++) {
            // ---- stage B for this 32-k half ----
#pragma unroll
            for (int rd = 0; rd < KW * 2; rd++) {
                int slotBase = rd * 256 + wv * 64;
                int slot = slotBase + lane;
                int r = slot >> 2;
                int g = (slot & 3) ^ ((r >> 1) & 3);
                int ocr = oc0 + (r & 127);
                if (ocr > Cout - 1) ocr = Cout - 1;
                int kwi = r >> 7;
                gl_lds16(Wc + (size_t)ocr * K + kwi * Cin + ic0 + h * 32 + g * 8,
                         &sB[slotBase * 8]);
            }
            __syncthreads();
#pragma unroll
            for (int kw = 0; kw < KW; kw++) {
                const int abase = (kw & 1) ? EB : 0;
                const int aoff = kw >> 1;
#pragma unroll
                for (int s = 0; s < 2; s++) {
                    int ar = abase + wv * 32 + s * 16 + mrow + aoff;
                    short8 af = *(const short8*)&sA[ar * 64 + (((h * 4 + kq) ^ (ar & 7)) * 8)];
#pragma unroll
                    for (int n = 0; n < 8; n++) {
                        int br = kw * 128 + n * 16 + mrow;
                        short8 bf = *(const short8*)&sB[br * 32 + ((kq ^ ((br >> 1) & 3)) * 8)];
                        acc[s][n] = __builtin_amdgcn_mfma_f32_16x16x32_bf16(af, bf, acc[s][n], 0, 0, 0);
                    }
                }
            }
            __syncthreads();
        }
    }

    // ---- epilogue (verified C-layout: row=kq*4+r -> t, col=mrow -> oc) ----
    float bz[8];
#pragma unroll
    for (int n = 0; n < 8; n++) {
        int oc = oc0 + n * 16 + mrow;
        bz[n] = (oc < Cout) ? bias[oc] : 0.f;
    }
#pragma unroll
    for (int s = 0; s < 2; s++) {
        int tb = t0 + wv * 32 + s * 16 + kq * 4;
#pragma unroll
        for (int n = 0; n < 8; n++) {
            int oc = oc0 + n * 16 + mrow;
            if (oc >= Cout) continue;
#pragma unroll
            for (int r = 0; r < 4; r++) {
                int t = tb + r;
                if (t < Tout) outb[(size_t)t * Cout + oc] = f2b(fmaxf(acc[s][n][r] + bz[n], 0.f));
            }
        }
    }
}

// =================================================================
// Generic MFMA GEMM (head projection only), BF32 weight path.
// =================================================================
template <int KW, int STRIDE, int RELU, int OBF, int BF32>
__global__ __launch_bounds__(256) void conv_mfma(
    const ushort* __restrict__ A,
    const ushort* __restrict__ Wc,
    const float* __restrict__ Wf,
    const float* __restrict__ bias,
    void* __restrict__ outv,
    int Cin, int Cout, int Tout, int tBase, int uBase,
    long aStride, long oStride) {
    const int K = KW * Cin;
    const int nCh = K >> 5;
    const int t0 = tBase + blockIdx.x * 128;
    const int oc0 = blockIdx.y * 128;
    const int b = blockIdx.z;
    const ushort* Ab = A + (size_t)b * aStride;
    __shared__ ushort sA[4096];
    __shared__ ushort sB[4096];
    const int tid = threadIdx.x;
    const int lane = tid & 63;
    const int wv = tid >> 6;
    const int rsub = lane >> 2;
    const int kgW = (lane & 3) ^ ((lane >> 3) & 3);
    const int mrow = lane & 15;
    const int kq = lane >> 4;
    const int slot8 = (mrow * 4 + (kq ^ ((mrow >> 1) & 3))) * 8;

    f32x4 acc[2][8];
#pragma unroll
    for (int s = 0; s < 2; s++)
#pragma unroll
        for (int n = 0; n < 8; n++) acc[s][n] = (f32x4){0.f, 0.f, 0.f, 0.f};

    for (int c = 0; c < nCh; c++) {
#pragma unroll
        for (int j = 0; j < 2; j++) {
            int t = t0 + j * 64 + wv * 16 + rsub;
            if (t > Tout - 1) t = Tout - 1;
            int u = STRIDE * t - uBase;
            gl_lds16(Ab + (size_t)u * Cin + c * 32 + kgW * 8, &sA[(j * 64 + wv * 16) * 32]);
        }
#pragma unroll
        for (int j = 0; j < 2; j++) {
            int rowb = oc0 + j * 64 + wv * 16 + rsub;
            if (rowb > Cout - 1) rowb = Cout - 1;
            if (BF32) {
                const float* wp = Wf + (size_t)rowb * K + c * 32 + kgW * 8;
                float4 w0_ = *(const float4*)wp;
                float4 w1_ = *(const float4*)(wp + 4);
                short8 vals;
                vals[0] = (short)f2b(w0_.x); vals[1] = (short)f2b(w0_.y);
                vals[2] = (short)f2b(w0_.z); vals[3] = (short)f2b(w0_.w);
                vals[4] = (short)f2b(w1_.x); vals[5] = (short)f2b(w1_.y);
                vals[6] = (short)f2b(w1_.z); vals[7] = (short)f2b(w1_.w);
                *(short8*)&sB[(j * 64 + wv * 16) * 32 + lane * 8] = vals;
            } else {
                gl_lds16(Wc + (size_t)rowb * K + c * 32 + kgW * 8, &sB[(j * 64 + wv * 16) * 32]);
            }
        }
        __syncthreads();
        short8 a0 = *(const short8*)&sA[(wv * 32 + 0) * 32 + slot8];
        short8 a1 = *(const short8*)&sA[(wv * 32 + 16) * 32 + slot8];
#pragma unroll
        for (int n = 0; n < 8; n++) {
            short8 bf = *(const short8*)&sB[(n * 16) * 32 + slot8];
            acc[0][n] = __builtin_amdgcn_mfma_f32_16x16x32_bf16(a0, bf, acc[0][n], 0, 0, 0);
            acc[1][n] = __builtin_amdgcn_mfma_f32_16x16x32_bf16(a1, bf, acc[1][n], 0, 0, 0);
        }
        __syncthreads();
    }
    float* outf = (float*)outv + (size_t)b * oStride;
    ushort* outh = (ushort*)outv + (size_t)b * oStride;
    float bz[8];
#pragma unroll
    for (int n = 0; n < 8; n++) {
        int oc = oc0 + n * 16 + mrow;
        bz[n] = (oc < Cout) ? bias[oc] : 0.f;
    }
#pragma unroll
    for (int s = 0; s < 2; s++) {
        int tb = t0 + wv * 32 + s * 16 + kq * 4;
#pragma unroll
        for (int n = 0; n < 8; n++) {
            int oc = oc0 + n * 16 + mrow;
            if (oc >= Cout) continue;
#pragma unroll
            for (int r = 0; r < 4; r++) {
                int t = tb + r;
                if (t < Tout) {
                    float v = acc[s][n][r] + bz[n];
                    if (RELU) v = fmaxf(v, 0.f);
                    if (OBF) outh[(size_t)t * Cout + oc] = f2b(v);
                    else outf[(size_t)t * Cout + oc] = v;
                }
            }
        }
    }
}

// =================================================================
// Split-K GEMM (transformer): A bf16 [256][K], W fp32 [M][K] -> fp32
// partial slabs outp[kc*oSlab + t*M + oc]; kc==0 slab carries bias.
// =================================================================
__global__ __launch_bounds__(256) void gemm_sk(
    const ushort* __restrict__ A, const float* __restrict__ Wf,
    const float* __restrict__ bias, float* __restrict__ outp,
    int M, int K, int KCH, long oSlab) {
    __shared__ ushort sA[4096];
    __shared__ ushort sB[4096];
    const int tid = threadIdx.x;
    const int lane = tid & 63;
    const int wv = tid >> 6;
    const int rsub = lane >> 2;
    const int kgW = (lane & 3) ^ ((lane >> 3) & 3);
    const int mrow = lane & 15;
    const int kq = lane >> 4;
    const int slot8 = (mrow * 4 + (kq ^ ((mrow >> 1) & 3))) * 8;
    const int t0 = blockIdx.x * 128;
    const int oc0 = blockIdx.y * 128;
    const int kc = blockIdx.z;
    const int k0 = kc * KCH;

    f32x4 acc[2][8];
#pragma unroll
    for (int s = 0; s < 2; s++)
#pragma unroll
        for (int n = 0; n < 8; n++) acc[s][n] = (f32x4){0.f, 0.f, 0.f, 0.f};

    const int nIt = KCH >> 5;
    for (int c = 0; c < nIt; c++) {
        const int kk = k0 + (c << 5);
#pragma unroll
        for (int j = 0; j < 2; j++) {
            int t = t0 + j * 64 + wv * 16 + rsub;
            gl_lds16(A + (size_t)t * K + kk + kgW * 8, &sA[(j * 64 + wv * 16) * 32]);
        }
#pragma unroll
        for (int j = 0; j < 2; j++) {
            int rowb = oc0 + j * 64 + wv * 16 + rsub;
            const float* wp = Wf + (size_t)rowb * K + kk + kgW * 8;
            float4 w0_ = *(const float4*)wp;
            float4 w1_ = *(const float4*)(wp + 4);
            short8 vals;
            vals[0] = (short)f2b(w0_.x); vals[1] = (short)f2b(w0_.y);
            vals[2] = (short)f2b(w0_.z); vals[3] = (short)f2b(w0_.w);
            vals[4] = (short)f2b(w1_.x); vals[5] = (short)f2b(w1_.y);
            vals[6] = (short)f2b(w1_.z); vals[7] = (short)f2b(w1_.w);
            *(short8*)&sB[(j * 64 + wv * 16) * 32 + lane * 8] = vals;
        }
        __syncthreads();
        short8 a0 = *(const short8*)&sA[(wv * 32 + 0) * 32 + slot8];
        short8 a1 = *(const short8*)&sA[(wv * 32 + 16) * 32 + slot8];
#pragma unroll
        for (int n = 0; n < 8; n++) {
            short8 bf = *(const short8*)&sB[(n * 16) * 32 + slot8];
            acc[0][n] = __builtin_amdgcn_mfma_f32_16x16x32_bf16(a0, bf, acc[0][n], 0, 0, 0);
            acc[1][n] = __builtin_amdgcn_mfma_f32_16x16x32_bf16(a1, bf, acc[1][n], 0, 0, 0);
        }
        __syncthreads();
    }

    float* op = outp + (size_t)kc * oSlab;
#pragma unroll
    for (int s = 0; s < 2; s++) {
        int tb = t0 + wv * 32 + s * 16 + kq * 4;
#pragma unroll
        for (int n = 0; n < 8; n++) {
            int oc = oc0 + n * 16 + mrow;
            float bz = (kc == 0) ? bias[oc] : 0.f;
#pragma unroll
            for (int r = 0; r < 4; r++) {
                op[(size_t)(tb + r) * M + oc] = acc[s][n][r] + bz;
            }
        }
    }
}

// ---------------- relu(sum of nP slabs) -> bf16 ----------------
__global__ __launch_bounds__(256) void relu_cast(const float* __restrict__ p,
                                                 ushort* __restrict__ o,
                                                 long n, long slab, int nP) {
    for (long i = (long)blockIdx.x * 1024 + threadIdx.x; i < n; i += (long)gridDim.x * 1024) {
#pragma unroll
        for (int j = 0; j < 4; j++) {
            long k = i + (long)j * 256;
            if (k < n) {
                float v = 0.f;
                for (int q = 0; q < nP; q++) v += p[k + q * slab];
                o[k] = f2b(fmaxf(v, 0.f));
            }
        }
    }
}

// =================================================================
// conv0 as MFMA GEMM
// =================================================================
__global__ __launch_bounds__(256) void conv0_mfma(const float* __restrict__ x,
                                                  const ushort* __restrict__ w0pad,
                                                  const float* __restrict__ b0,
                                                  ushort* __restrict__ c0,
                                                  int uBase, int nU) {
    __shared__ ushort sA[4096];
    __shared__ ushort sB[4096];
    const int tid = threadIdx.x;
    const int lane = tid & 63;
    const int wv = tid >> 6;
    const int rsub = lane >> 2;
    const int kgW = (lane & 3) ^ ((lane >> 3) & 3);
    const int mrow = lane & 15;
    const int kq = lane >> 4;
    const int slot8 = (mrow * 4 + (kq ^ ((mrow >> 1) & 3))) * 8;
    const int r0 = blockIdx.x * 128;
    const int oc0 = blockIdx.y * 128;

    f32x4 acc[2][8];
#pragma unroll
    for (int s = 0; s < 2; s++)
#pragma unroll
        for (int n = 0; n < 8; n++) acc[s][n] = (f32x4){0.f, 0.f, 0.f, 0.f};

#pragma unroll
    for (int j = 0; j < 2; j++) {
        int r = r0 + j * 64 + wv * 16 + rsub;
        if (r > nU - 1) r = nU - 1;
        const float* xp = x + (size_t)5 * (uBase + r);
        short8 vals = (short8){0, 0, 0, 0, 0, 0, 0, 0};
        if (kgW == 0) {
#pragma unroll
            for (int q = 0; q < 8; q++) vals[q] = (short)f2b(xp[q]);
        } else if (kgW == 1) {
            vals[0] = (short)f2b(xp[8]);
            vals[1] = (short)f2b(xp[9]);
        }
        *(short8*)&sA[(j * 64 + wv * 16) * 32 + lane * 8] = vals;
    }
#pragma unroll
    for (int j = 0; j < 2; j++) {
        int rowb = oc0 + j * 64 + wv * 16 + rsub;
        gl_lds16(w0pad + (size_t)rowb * 32 + kgW * 8, &sB[(j * 64 + wv * 16) * 32]);
    }
    __syncthreads();
    short8 a0 = *(const short8*)&sA[(wv * 32 + 0) * 32 + slot8];
    short8 a1 = *(const short8*)&sA[(wv * 32 + 16) * 32 + slot8];
#pragma unroll
    for (int n = 0; n < 8; n++) {
        short8 bf = *(const short8*)&sB[(n * 16) * 32 + slot8];
        acc[0][n] = __builtin_amdgcn_mfma_f32_16x16x32_bf16(a0, bf, acc[0][n], 0, 0, 0);
        acc[1][n] = __builtin_amdgcn_mfma_f32_16x16x32_bf16(a1, bf, acc[1][n], 0, 0, 0);
    }
#pragma unroll
    for (int s = 0; s < 2; s++) {
        int rb = r0 + wv * 32 + s * 16 + kq * 4;
#pragma unroll
        for (int n = 0; n < 8; n++) {
            int oc = oc0 + n * 16 + mrow;
            float bz = b0[oc];
#pragma unroll
            for (int r = 0; r < 4; r++) {
                int rr = rb + r;
                if (rr < nU) c0[(size_t)rr * 512 + oc] = f2b(fmaxf(acc[s][n][r] + bz, 0.f));
            }
        }
    }
}

// ---------------- conv-weight permute+cast ----------------
__global__ __launch_bounds__(256) void convw_kernel(
    const float* __restrict__ w1, const float* __restrict__ w2, const float* __restrict__ w3,
    const float* __restrict__ w4, const float* __restrict__ w5, const float* __restrict__ w6,
    const float* __restrict__ w0, ushort* __restrict__ dst, ushort* __restrict__ dw0) {
    const int z = blockIdx.y;
    const int COUTS[6] = {512, 512, 512, 512, 512, 768};
    const int KWS[6] = {3, 3, 3, 2, 2, 2};
    const long OFFS[6] = {0, 786432, 1572864, 2359296, 2883584, 3407872};
    const float* srcs[6] = {w1, w2, w3, w4, w5, w6};
    if (z == 6) {
        for (int o = blockIdx.x * 256 + threadIdx.x; o < 512 * 32; o += gridDim.x * 256) {
            int oc = o >> 5, q = o & 31;
            dw0[o] = (q < 10) ? f2b(w0[oc * 10 + q]) : (ushort)0;
        }
        return;
    }
    const float* src = srcs[z];
    ushort* d = dst + OFFS[z];
    const int Cin = 512, Kw = KWS[z];
    const int K = Cin * Kw;
    const long n = (long)COUTS[z] * K;
    for (long o = blockIdx.x * 256 + threadIdx.x; o < n; o += (long)gridDim.x * 256) {
        long oc = o / K;
        int rem = (int)(o - oc * K);
        int kw = rem / Cin, ic = rem - kw * Cin;
        d[o] = f2b(src[(oc * Cin + ic) * Kw + kw]);
    }
}

// ---------------- scores ----------------
__global__ __launch_bounds__(256) void scores_kernel(const ushort* __restrict__ feats,
                                                     const float* __restrict__ v,
                                                     float* __restrict__ scores) {
    int b = blockIdx.y;
    int t = blockIdx.x * 4 + (threadIdx.x >> 6);
    if (t >= TP_) return;
    int lane = threadIdx.x & 63;
    const ushort* f = feats + ((size_t)b * TP_ + t) * DMODEL + lane * 12;
    float acc = 0.f;
#pragma unroll
    for (int q = 0; q < 12; q++) acc = fmaf(b2f(f[q]), v[lane * 12 + q], acc);
    acc = wave_reduce_sum(acc);
    if (lane == 0) scores[b * TP_ + t] = acc;
}

// ---------------- per-segment softmax pooling + pos_emb ----------------
__global__ __launch_bounds__(256) void pool_kernel(const ushort* __restrict__ featsAll,
                                                   const float* __restrict__ scoresAll,
                                                   const int* __restrict__ seg_bounds,
                                                   const int* __restrict__ n_segs,
                                                   const float* __restrict__ pos_emb,
                                                   float* __restrict__ tokens,
                                                   ushort* __restrict__ tokens_bf) {
    __shared__ float scratch[4];
    __shared__ float wgt[512];
    int s = blockIdx.x, b = blockIdx.y, tid = threadIdx.x;
    float* tout = tokens + ((size_t)b * SMAX_ + s) * DMODEL;
    ushort* tbf = tokens_bf + ((size_t)b * SMAX_ + s) * DMODEL;
    int ns = n_segs[b];
    if (s >= ns) {
        for (int c = tid; c < DMODEL; c += 256) {
            float v = pos_emb[s * DMODEL + c];
            tout[c] = v; tbf[c] = f2b(v);
        }
        return;
    }
    const float* sc = scoresAll + b * TP_;
    int b0 = seg_bounds[b * (SMAX_ + 1) + s];
    int b1 = seg_bounds[b * (SMAX_ + 1) + s + 1];
    int st = min(max(b0, 0), TP_ - 1);
    int en = max(st + 1, min(max(b1, 0), TP_));
    float lm = -1e30f;
    for (int t = st + tid; t < en; t += 256) lm = fmaxf(lm, sc[t]);
    float m = block_reduce_max(lm, scratch);
    float ls = 0.f;
    for (int t = st + tid; t < en; t += 256) ls += __expf(sc[t] - m);
    float den = block_reduce_sum(ls, scratch);
    float inv = 1.f / den;
    for (int t = st + tid; t < en; t += 256) wgt[t - st] = __expf(sc[t] - m) * inv;
    __syncthreads();
    int len = en - st;
    const ushort* f = featsAll + ((size_t)b * TP_ + st) * DMODEL;
    float a0 = 0.f, a1 = 0.f, a2 = 0.f;
    for (int t = 0; t < len; t++) {
        float wv = wgt[t];
        const ushort* fr = f + (size_t)t * DMODEL;
        a0 = fmaf(wv, b2f(fr[tid]), a0);
        a1 = fmaf(wv, b2f(fr[tid + 256]), a1);
        a2 = fmaf(wv, b2f(fr[tid + 512]), a2);
    }
    float v0 = a0 + pos_emb[s * DMODEL + tid];
    float v1 = a1 + pos_emb[s * DMODEL + tid + 256];
    float v2 = a2 + pos_emb[s * DMODEL + tid + 512];
    tout[tid] = v0; tout[tid + 256] = v1; tout[tid + 512] = v2;
    tbf[tid] = f2b(v0); tbf[tid + 256] = f2b(v1); tbf[tid + 512] = f2b(v2);
}

// ---------------- attention: qkv from nP fp32 partial slabs ----------------
__global__ __launch_bounds__(256) void attn_kernel(const float* __restrict__ qkv_p,
                                                   const int* __restrict__ n_segs,
                                                   ushort* __restrict__ o, long slab, int nP) {
    __shared__ float sK[64][68];
    __shared__ float sV[64][68];
    __shared__ float sS[64][68];
    int h = blockIdx.x, b = blockIdx.y, tid = threadIdx.x;
    int ns = n_segs[b];
    const float* base = qkv_p + (size_t)b * 64 * 2304 + h * 64;
    for (int idx = tid; idx < 4096; idx += 256) {
        int s_ = idx >> 6, d = idx & 63;
        size_t kofs = (size_t)s_ * 2304 + 768 + d;
        size_t vofs = (size_t)s_ * 2304 + 1536 + d;
        float kv = 0.f, vv = 0.f;
        for (int p = 0; p < nP; p++) { kv += base[kofs + p * slab]; vv += base[vofs + p * slab]; }
        sK[s_][d] = kv; sV[s_][d] = vv;
    }
    __syncthreads();
    int qr = tid >> 2;
    int c0 = (tid & 3) * 16;
    const float* qrow = base + (size_t)qr * 2304;
    float acc[16];
#pragma unroll
    for (int j = 0; j < 16; j++) acc[j] = 0.f;
    for (int d = 0; d < 64; d += 4) {
        float4 qv = make_float4(0.f, 0.f, 0.f, 0.f);
        for (int p = 0; p < nP; p++) {
            float4 qp = *(const float4*)(qrow + p * slab + d);
            qv.x += qp.x; qv.y += qp.y; qv.z += qp.z; qv.w += qp.w;
        }
#pragma unroll
        for (int j = 0; j < 16; j++) {
            float4 kv = *(const float4*)&sK[c0 + j][d];
            acc[j] += qv.x * kv.x + qv.y * kv.y + qv.z * kv.z + qv.w * kv.w;
        }
    }
#pragma unroll
    for (int j = 0; j < 16; j++) {
        int kc = c0 + j;
        float vv = acc[j] * 0.125f;
        if (kc >= ns) vv = -1e9f;
        sS[qr][kc] = vv;
    }
    __syncthreads();
    if (tid < 64) {
        float m = -1e30f;
#pragma unroll 4
        for (int k = 0; k < 64; k++) m = fmaxf(m, sS[tid][k]);
        float ssum = 0.f;
#pragma unroll 4
        for (int k = 0; k < 64; k++) {
            float e = __expf(sS[tid][k] - m);
            sS[tid][k] = e;
            ssum += e;
        }
        float inv = 1.f / ssum;
#pragma unroll 4
        for (int k = 0; k < 64; k++) sS[tid][k] *= inv;
    }
    __syncthreads();
    float4 oacc[4];
#pragma unroll
    for (int j = 0; j < 4; j++) oacc[j] = make_float4(0.f, 0.f, 0.f, 0.f);
    for (int k = 0; k < 64; k++) {
        float wv = sS[qr][k];
#pragma unroll
        for (int j4 = 0; j4 < 4; j4++) {
            float4 vv = *(const float4*)&sV[k][c0 + j4 * 4];
            oacc[j4].x = fmaf(wv, vv.x, oacc[j4].x);
            oacc[j4].y = fmaf(wv, vv.y, oacc[j4].y);
            oacc[j4].z = fmaf(wv, vv.z, oacc[j4].z);
            oacc[j4].w = fmaf(wv, vv.w, oacc[j4].w);
        }
    }
    ushort* orow = o + ((size_t)b * 64 + qr) * DMODEL + h * 64 + c0;
#pragma unroll
    for (int j4 = 0; j4 < 4; j4++) {
        orow[j4 * 4 + 0] = f2b(oacc[j4].x);
        orow[j4 * 4 + 1] = f2b(oacc[j4].y);
        orow[j4 * 4 + 2] = f2b(oacc[j4].z);
        orow[j4 * 4 + 3] = f2b(oacc[j4].w);
    }
}

// ---------------- layernorm; residual = sum of nP fp32 slabs ----------------
__global__ __launch_bounds__(256) void ln_kernel(const float* __restrict__ x,
                                                 const float* __restrict__ rP, int nP, long rSlab,
                                                 const float* __restrict__ w,
                                                 const float* __restrict__ b,
                                                 float* __restrict__ out,
                                                 ushort* __restrict__ outbf) {
    __shared__ float scratch[4];
    int row = blockIdx.x, tid = threadIdx.x;
    const float* xr = x + (size_t)row * DMODEL;
    float v0 = xr[tid], v1 = xr[tid + 256], v2 = xr[tid + 512];
    for (int p = 0; p < nP; p++) {
        const float* rr = rP + (size_t)p * rSlab + (size_t)row * DMODEL;
        v0 += rr[tid]; v1 += rr[tid + 256]; v2 += rr[tid + 512];
    }
    float mean = block_reduce_sum(v0 + v1 + v2, scratch) * (1.f / DMODEL);
    float d0 = v0 - mean, d1 = v1 - mean, d2 = v2 - mean;
    float var = block_reduce_sum(d0 * d0 + d1 * d1 + d2 * d2, scratch) * (1.f / DMODEL);
    float inv = rsqrtf(var + 1e-5f);
    float o0 = d0 * inv * w[tid] + b[tid];
    float o1 = d1 * inv * w[tid + 256] + b[tid + 256];
    float o2 = d2 * inv * w[tid + 512] + b[tid + 512];
    float* orow = out + (size_t)row * DMODEL;
    orow[tid] = o0; orow[tid + 256] = o1; orow[tid + 512] = o2;
    if (outbf) {
        ushort* obf = outbf + (size_t)row * DMODEL;
        obf[tid] = f2b(o0); obf[tid + 256] = f2b(o1); obf[tid + 512] = f2b(o2);
    }
}

// ---------------- pad mask output ----------------
__global__ void mask_kernel(const int* __restrict__ n_segs, float* __restrict__ mout) {
    int i = threadIdx.x;
    int b = i >> 6, s = i & 63;
    mout[i] = (s >= n_segs[b]) ? 1.0f : 0.0f;
}

// ---------------- host ----------------
extern "C" void kernel_launch(void* const* d_in, const int* in_sizes, int n_in,
                              void* d_out, int out_size, void* d_ws, size_t ws_size,
                              hipStream_t stream) {
    const float* x = (const float*)d_in[0];
    const int* seg_bounds = (const int*)d_in[1];
    const int* n_segs = (const int*)d_in[2];
    const float* cw[7], * cb[7];
    for (int i = 0; i < 7; i++) { cw[i] = (const float*)d_in[3 + 2 * i]; cb[i] = (const float*)d_in[4 + 2 * i]; }
    const float* attn_v = (const float*)d_in[17];
    const float* pos_emb = (const float*)d_in[18];
    const float* in_w = (const float*)d_in[19];
    const float* in_b = (const float*)d_in[20];
    const float* out_w = (const float*)d_in[21];
    const float* out_b = (const float*)d_in[22];
    const float* ff1_w = (const float*)d_in[23];
    const float* ff1_b = (const float*)d_in[24];
    const float* ff2_w = (const float*)d_in[25];
    const float* ff2_b = (const float*)d_in[26];
    const float* ln1_w = (const float*)d_in[27];
    const float* ln1_b = (const float*)d_in[28];
    const float* ln2_w = (const float*)d_in[29];
    const float* ln2_b = (const float*)d_in[30];
    const float* fln_w = (const float*)d_in[31];
    const float* fln_b = (const float*)d_in[32];
    const float* proj_w = (const float*)d_in[33];
    const float* proj_b = (const float*)d_in[34];

    mask_kernel<<<1, 256, 0, stream>>>(n_segs, (float*)d_out + 256 * NCLS);

    size_t off = 0;
    auto alloc = [&](size_t bytes) {
        void* p = (char*)d_ws + off;
        off += (bytes + 255) & ~(size_t)255;
        return p;
    };
    ushort* wbc = (ushort*)alloc(4194304ULL * 2);
    ushort* w0pad = (ushort*)alloc(512ULL * 32 * 2);
    ushort* c0buf = (ushort*)alloc((size_t)16001 * 512 * 2);   // 16.39 MB (reused)
    ushort* out1 = (ushort*)alloc((size_t)15999 * 512 * 2);    // 16.38 MB (reused)
    ushort* out4 = (ushort*)alloc((size_t)4 * 1999 * 512 * 2); // 8.19 MB (reused)
    float* scores = (float*)alloc((size_t)4 * TP_ * 4);
    float* tokens = (float*)alloc((size_t)256 * DMODEL * 4);
    ushort* tokens_bf = (ushort*)alloc((size_t)256 * DMODEL * 2);
    ushort* oall_bf = (ushort*)alloc((size_t)256 * DMODEL * 2);
    float* ybuf = (float*)alloc((size_t)256 * DMODEL * 4);
    ushort* ybf = (ushort*)alloc((size_t)256 * DMODEL * 2);
    if (off > ws_size) return;  // diagnostic bail

    // conv-phase aliases
    ushort* out2b = c0buf;
    ushort* out3b = out1 + (size_t)12000 * 512;
    ushort* out5 = c0buf;
    ushort* feats = out1;
    // transformer-phase aliases
    float* qkv_p = (float*)c0buf;                           // 4 x 256x2304 = 9.44 MB
    float* ffh_p = (float*)c0buf + (size_t)4 * 256 * 2304;  // 3 x 256x2048 = 6.29 MB (tot 15.73 <= 16.39)
    ushort* ffh_bf = (ushort*)out4;                         // 1.05 MB
    float* tmp_p = (float*)((char*)out4 + (size_t)256 * 2048 * 2);  // 8 x 256x768 = 6.29 (tot 7.34 <= 8.19)

    ushort* wc1 = wbc, * wc2 = wbc + 786432, * wc3 = wbc + 1572864,
          * wc4 = wbc + 2359296, * wc5 = wbc + 2883584, * wc6 = wbc + 3407872;

    convw_kernel<<<dim3(512, 7), 256, 0, stream>>>(cw[1], cw[2], cw[3], cw[4], cw[5], cw[6],
                                                   cw[0], wbc, w0pad);

    // ---- conv stack (kw-inner MFMA; conv0+conv1 in two u-chunks) ----
    for (int b = 0; b < BATCH; b++) {
        const float* xb = x + (size_t)b * TIN0;
        conv0_mfma<<<dim3(126, 4), 256, 0, stream>>>(xb, w0pad, cb[0], c0buf, 0, 16001);
        convT_mfma<3><<<dim3(63, 4, 1), 256, 0, stream>>>(
            c0buf, wc1, cb[1], out1, 512, 512, 15999, 0, 0, 16000, 0, 0);
        conv0_mfma<<<dim3(125, 4), 256, 0, stream>>>(xb, w0pad, cb[0], c0buf, 16000, 15999);
        convT_mfma<3><<<dim3(63, 4, 1), 256, 0, stream>>>(
            c0buf, wc1, cb[1], out1, 512, 512, 15999, 8000, 16000, 15998, 0, 0);
        convT_mfma<3><<<dim3(63, 4, 1), 256, 0, stream>>>(
            out1, wc2, cb[2], out2b, 512, 512, 7999, 0, 0, 15998, 0, 0);
        convT_mfma<3><<<dim3(32, 4, 1), 256, 0, stream>>>(
            out2b, wc3, cb[3], out3b, 512, 512, 3999, 0, 0, 7998, 0, 0);
        convT_mfma<2><<<dim3(16, 4, 1), 256, 0, stream>>>(
            out3b, wc4, cb[4], out4 + (size_t)b * 1999 * 512, 512, 512, 1999, 0, 0, 3998, 0, 0);
    }
    convT_mfma<2><<<dim3(8, 4, BATCH), 256, 0, stream>>>(
        out4, wc5, cb[5], out5, 512, 512, 999, 0, 0, 1998,
        (long)1999 * 512, (long)999 * 512);
    convT_mfma<2><<<dim3(4, 6, BATCH), 256, 0, stream>>>(
        out5, wc6, cb[6], feats, 512, 768, 499, 0, 0, 998,
        (long)999 * 512, (long)499 * 768);

    // ---- pooling ----
    scores_kernel<<<dim3(125, 4), 256, 0, stream>>>(feats, attn_v, scores);
    pool_kernel<<<dim3(SMAX_, 4), 256, 0, stream>>>(feats, scores, seg_bounds, n_segs,
                                                    pos_emb, tokens, tokens_bf);

    // ---- transformer (split-K GEMMs) ----
    const long qkvSlab = (long)256 * 2304;
    const long tmpSlab = (long)256 * 768;
    const long ffhSlab = (long)256 * 2048;
    for (int l = 0; l < NLAYER; l++) {
        const float* iw = in_w + (size_t)l * 2304 * DMODEL;
        const float* ib = in_b + (size_t)l * 2304;
        const float* ow = out_w + (size_t)l * DMODEL * DMODEL;
        const float* ob = out_b + (size_t)l * DMODEL;
        const float* f1w = ff1_w + (size_t)l * FFDIM * DMODEL;
        const float* f1b = ff1_b + (size_t)l * FFDIM;
        const float* f2w = ff2_w + (size_t)l * DMODEL * FFDIM;
        const float* f2b_ = ff2_b + (size_t)l * DMODEL;

        gemm_sk<<<dim3(2, 18, 4), 256, 0, stream>>>(tokens_bf, iw, ib, qkv_p, 2304, 768, 192, qkvSlab);
        attn_kernel<<<dim3(12, 4), 256, 0, stream>>>(qkv_p, n_segs, oall_bf, qkvSlab, 4);
        gemm_sk<<<dim3(2, 6, 4), 256, 0, stream>>>(oall_bf, ow, ob, tmp_p, 768, 768, 192, tmpSlab);
        ln_kernel<<<256, 256, 0, stream>>>(tokens, tmp_p, 4, tmpSlab,
                                           ln1_w + l * DMODEL, ln1_b + l * DMODEL, tokens, tokens_bf);
        gemm_sk<<<dim3(2, 16, 3), 256, 0, stream>>>(tokens_bf, f1w, f1b, ffh_p, 2048, 768, 256, ffhSlab);
        relu_cast<<<512, 256, 0, stream>>>(ffh_p, ffh_bf, (long)256 * 2048, ffhSlab, 3);
        gemm_sk<<<dim3(2, 6, 8), 256, 0, stream>>>(ffh_bf, f2w, f2b_, tmp_p, 768, 2048, 256, tmpSlab);
        ln_kernel<<<256, 256, 0, stream>>>(tokens, tmp_p, 8, tmpSlab,
                                           ln2_w + l * DMODEL, ln2_b + l * DMODEL, tokens, tokens_bf);
    }

    // ---- head ----
    ln_kernel<<<256, 256, 0, stream>>>(tokens, nullptr, 0, 0, fln_w, fln_b, ybuf, ybf);
    conv_mfma<1, 1, 0, 0, 1><<<dim3(2, 1, 1), 256, 0, stream>>>(
        ybf, nullptr, proj_w, proj_b, (float*)d_out, 768, NCLS, 256, 0, 0, 0, 0);
}